// Round 18
// baseline (181.703 us; speedup 1.0000x reference)
//
#include <hip/hip_runtime.h>
#include <math.h>

#define NTOT 262144   // total nodes
#define BG   64       // graphs
#define NNPG 4096     // nodes per graph
#define ET   1048576  // directed edges
#define EPG  16384    // edges per graph
#define EPB  4096     // edges per sub-block (4 sub-blocks/graph)
#define HD   128
#define LD   64
#define NSEG 129
#define TN   256
#define MCAP ET       // miss-list capacity (int2 entries)

// XCD-bijective swizzle: all 4 sub-blocks of graph g share (b&7) -> one XCD L2
__device__ __forceinline__ void swz(int b, int& g, int& j){
  int xcd = b & 7, q = b >> 3;
  g = (q >> 2)*8 + xcd;
  j = q & 3;
}

// ---- shared tabrows body: rows {0, nf} via q-split partials + rare extras ----
// caller provides 1024 threads and the shared arrays.
__device__ __forceinline__ void tabrows_body(
    int g, int tid,
    const float* __restrict__ wsrc, const float* __restrict__ bsrc,
    const float* __restrict__ w2, const int* __restrict__ segUsed,
    const int* __restrict__ nfA, float* __restrict__ ACbase,
    float* ws, float* bs, float* tsh, int* ks, int* rr,
    float (*red)[128][4])
{
  int k = tid & 127, qg = tid >> 7;
  if (qg == 0){
    float w = wsrc[g*HD + k], b = bsrc[k];
    float t; int kind;
    if (w != 0.0f){ t = -b / w; kind = (w > 0.0f) ? 0 : 1; }
    else          { t = INFINITY; kind = 2; }
    ws[k] = w; bs[k] = b; tsh[k] = t; ks[k] = kind;
  }
  __syncthreads();
  if (qg == 0){          // ranks (needed only for rare extra rows)
    float t = tsh[k];
    int r = 0;
    for (int q = 0; q < 128; q++){
      if (ks[q] != 2){
        float tq = tsh[q];
        if (tq < t || (tq == t && q < k)) r++;
      }
    }
    rr[k] = r;
  }
  float a0=0.f, c0=0.f, an=0.f, cn=0.f;
  #pragma unroll
  for (int u = 0; u < 16; u++){
    int q = qg*16 + u;
    float v = w2[q*HD + k];
    int kd = ks[q];
    float wq = ws[q], bq = bs[q];
    bool m0 = (kd == 1) || (kd == 2 && bq > 0.f);
    bool mn = (kd == 0) || (kd == 2 && bq > 0.f);
    float wv = wq*v, bv = bq*v;
    a0 += m0 ? wv : 0.f; c0 += m0 ? bv : 0.f;
    an += mn ? wv : 0.f; cn += mn ? bv : 0.f;
  }
  red[qg][k][0]=a0; red[qg][k][1]=c0; red[qg][k][2]=an; red[qg][k][3]=cn;
  __syncthreads();
  int nf = nfA[g];
  float* ACg = ACbase + (size_t)g*NSEG*256;
  int base = (k>>2)*8 + (k&3);
  if (qg == 0){
    float A0=0.f,C0=0.f,An=0.f,Cn=0.f;
    #pragma unroll
    for (int p = 0; p < 8; p++){
      A0+=red[p][k][0]; C0+=red[p][k][1]; An+=red[p][k][2]; Cn+=red[p][k][3];
    }
    ACg[base] = A0; ACg[base+4] = C0;
    ACg[(size_t)nf*256 + base] = An; ACg[(size_t)nf*256 + base + 4] = Cn;
  }
  __syncthreads();
  for (int wd = 0; wd < 5; wd++){
    unsigned m = (unsigned)segUsed[g*8 + wd];
    if (wd == 0) m &= ~1u;
    if ((nf >> 5) == wd) m &= ~(1u << (nf & 31));
    while (m){
      int bit = __ffs(m) - 1;
      m &= m - 1;
      int s = wd*32 + bit;
      float pa=0.f, pc=0.f;
      #pragma unroll
      for (int u = 0; u < 16; u++){
        int q = qg*16 + u;
        int kd = ks[q];
        bool act = (kd == 0) ? (rr[q] < s) : (kd == 1) ? (rr[q] >= s) : (bs[q] > 0.f);
        float v = act ? w2[q*HD + k] : 0.f;
        pa = fmaf(ws[q], v, pa); pc = fmaf(bs[q], v, pc);
      }
      red[qg][k][0]=pa; red[qg][k][1]=pc;
      __syncthreads();
      if (qg == 0){
        float A=0.f,C=0.f;
        #pragma unroll
        for (int p = 0; p < 8; p++){ A+=red[p][k][0]; C+=red[p][k][1]; }
        ACg[(size_t)s*256 + base] = A; ACg[(size_t)s*256 + base + 4] = C;
      }
      __syncthreads();
    }
  }
}

// ---- count: LDS histogram per sub-block -> planar cntJ; block 256 = rider:
//      tab1a (t1,nf1) + zero hgsum/mcnt/segU1/segU (replaces all memsets) ----
__global__ void __launch_bounds__(1024) k_count(const int* __restrict__ ei,
                                                const float* __restrict__ w1,
                                                const float* __restrict__ b1,
                                                int* __restrict__ cntJ,
                                                float* __restrict__ t1, int* __restrict__ nfp,
                                                float* __restrict__ hgsum,
                                                int* __restrict__ mcnt,
                                                int* __restrict__ segU1,
                                                int* __restrict__ segU){
  __shared__ int h[NNPG];
  int tid = threadIdx.x;
  if (blockIdx.x == 256){
    for (int idx = tid; idx < BG*HD; idx += 1024) hgsum[idx] = 0.f;
    if (tid < 2) mcnt[tid] = 0;
    if (tid < 8) segU1[tid] = 0;
    if (tid < BG*8) segU[tid] = 0;
    if (tid < 128){
      float w = w1[tid], b = b1[tid];
      float t; int kind;
      if (w != 0.0f){ t = -b / w; kind = (w > 0.0f) ? 0 : 1; }
      else          { t = INFINITY; kind = 2; }
      h[tid] = kind;
      t1[tid] = t;
    }
    __syncthreads();
    if (tid == 0){
      int c = 0;
      for (int q = 0; q < 128; q++) c += (h[q] != 2) ? 1 : 0;
      nfp[0] = c;
    }
    return;
  }
  int g, j; swz(blockIdx.x, g, j);
  #pragma unroll
  for (int k = tid; k < NNPG; k += 1024) h[k] = 0;
  __syncthreads();
  int gbase = g*NNPG;
  const int4* dsts4 = (const int4*)(ei + ET + g*EPG + j*EPB);
  int4 D = dsts4[tid];
  atomicAdd(&h[D.x - gbase], 1); atomicAdd(&h[D.y - gbase], 1);
  atomicAdd(&h[D.z - gbase], 1); atomicAdd(&h[D.w - gbase], 1);
  __syncthreads();
  int* plane = cntJ + j*NTOT + gbase;
  #pragma unroll
  for (int k = tid; k < NNPG; k += 1024) plane[k] = h[k];
}

// ---- edge pass 1 (fused dinv/xd): per-dest sums of (d_s*x_s, d_s) ----
// Each block computes its graph's xd into LDS; sub-block 0 also writes it out.
__global__ void __launch_bounds__(1024) k_edge1(
    const int* __restrict__ ei, const int* __restrict__ cntJ,
    const float* __restrict__ x, float2* __restrict__ xd,
    float2* __restrict__ accJ)
{
  __shared__ float2 sxd[NNPG];    // 32 KB
  __shared__ float ax[NNPG];      // 16 KB
  __shared__ float s1[NNPG];      // 16 KB
  int tid = threadIdx.x;
  int g, j; swz(blockIdx.x, g, j);
  int gbase = g*NNPG;
  const int4* srcs4 = (const int4*)(ei + g*EPG + j*EPB);
  const int4* dsts4 = (const int4*)(ei + ET + g*EPG + j*EPB);
  int4 S = srcs4[tid], D = dsts4[tid];
  {
    int i0 = 4*tid;
    int4 c0 = *(const int4*)(cntJ + 0*NTOT + gbase + i0);
    int4 c1 = *(const int4*)(cntJ + 1*NTOT + gbase + i0);
    int4 c2 = *(const int4*)(cntJ + 2*NTOT + gbase + i0);
    int4 c3 = *(const int4*)(cntJ + 3*NTOT + gbase + i0);
    float4 xv = *(const float4*)(x + gbase + i0);
    float2 p0 = make_float2(xv.x, rsqrtf((float)(c0.x+c1.x+c2.x+c3.x) + 1.0f));
    float2 p1 = make_float2(xv.y, rsqrtf((float)(c0.y+c1.y+c2.y+c3.y) + 1.0f));
    float2 p2 = make_float2(xv.z, rsqrtf((float)(c0.z+c1.z+c2.z+c3.z) + 1.0f));
    float2 p3 = make_float2(xv.w, rsqrtf((float)(c0.w+c1.w+c2.w+c3.w) + 1.0f));
    sxd[i0+0] = p0; sxd[i0+1] = p1; sxd[i0+2] = p2; sxd[i0+3] = p3;
    if (j == 0){
      float4* xd4 = (float4*)(xd + gbase);
      xd4[2*tid+0] = make_float4(p0.x, p0.y, p1.x, p1.y);
      xd4[2*tid+1] = make_float4(p2.x, p2.y, p3.x, p3.y);
    }
    *(float4*)(ax + i0) = make_float4(0.f,0.f,0.f,0.f);
    *(float4*)(s1 + i0) = make_float4(0.f,0.f,0.f,0.f);
  }
  __syncthreads();
  #define P1(s_, d_) { float2 sd = sxd[(s_) - gbase]; int dl = (d_) - gbase; \
    atomicAdd(&ax[dl], sd.y * sd.x); \
    atomicAdd(&s1[dl], sd.y); }
  P1(S.x, D.x); P1(S.y, D.y); P1(S.z, D.z); P1(S.w, D.w);
  #undef P1
  __syncthreads();
  float4* ap = (float4*)(accJ + (size_t)j*NTOT + gbase);
  ap[2*tid+0] = make_float4(ax[4*tid+0], s1[4*tid+0], ax[4*tid+1], s1[4*tid+1]);
  ap[2*tid+1] = make_float4(ax[4*tid+2], s1[4*tid+2], ax[4*tid+3], s1[4*tid+3]);
}

// ---- pack per-node record: rec[i] = (d, d*ax, d*srow, segE) + segE bitmap ----
__global__ void k_pack(const float2* __restrict__ xd, const float2* __restrict__ accJ,
                       const float* __restrict__ t1,
                       float4* __restrict__ rec, float* __restrict__ srowA,
                       int* __restrict__ segU1){
  __shared__ float ts[128];
  __shared__ int used[8];
  int tid = threadIdx.x;
  if (tid < 128) ts[tid] = t1[tid];
  if (tid < 8) used[tid] = 0;
  __syncthreads();
  int i = blockIdx.x*256 + tid;
  float2 xdv = xd[i];
  float2 a0 = accJ[0*NTOT + i], a1 = accJ[1*NTOT + i];
  float2 a2 = accJ[2*NTOT + i], a3 = accJ[3*NTOT + i];
  float axs = (a0.x + a1.x) + (a2.x + a3.x);
  float s1s = (a0.y + a1.y) + (a2.y + a3.y);
  float di = xdv.y;
  float ax = di * (di * xdv.x + axs);
  float sr = di * (di + s1s);
  int sc = 0;
  for (int q = 0; q < 128; q++) sc += (ts[q] < ax) ? 1 : 0;
  rec[i] = make_float4(di, di*ax, di*sr, __int_as_float(sc));
  srowA[i] = sr;
  atomicOr(&used[sc>>5], 1u << (sc & 31));
  __syncthreads();
  if (tid < 8 && used[tid]) atomicOr(&segU1[tid], used[tid]);
}

// ---- edge pass 2 (encoder) + tabrows-enc rider (block 256) ----
__global__ void __launch_bounds__(1024) k_edge2enc(
    const int* __restrict__ ei, const float4* __restrict__ rec,
    const int* __restrict__ nfp, float4* __restrict__ sums4,
    int2* __restrict__ missL, int* __restrict__ mcnt,
    const float* __restrict__ enc_w1, const float* __restrict__ enc_b1,
    const float* __restrict__ enc_w2, const int* __restrict__ segU1,
    float* __restrict__ AC1)
{
  __shared__ union {
    struct { float sf[NNPG*4]; float4 sRec[NNPG]; } e;            // 128 KB
    struct { float ws[128], bs[128], tsh[128];
             int ks[128], rr[128]; float red[8][128][4]; } t;     // ~19 KB
  } u;
  int tid = threadIdx.x;
  if (blockIdx.x == 256){
    tabrows_body(0, tid, enc_w1, enc_b1, enc_w2, segU1, nfp, AC1,
                 u.t.ws, u.t.bs, u.t.tsh, u.t.ks, u.t.rr, u.t.red);
    return;
  }
  int g, j; swz(blockIdx.x, g, j);
  int gbase = g*NNPG;
  int nf = nfp[0];
  const int4* srcs4 = (const int4*)(ei + g*EPG + j*EPB);
  const int4* dsts4 = (const int4*)(ei + ET + g*EPG + j*EPB);
  int4 S = srcs4[tid], D = dsts4[tid];
  float4* sf4 = (float4*)u.e.sf;
  #pragma unroll
  for (int k = 0; k < 4; k++){
    sf4[4*tid + k] = make_float4(0.f,0.f,0.f,0.f);
    u.e.sRec[k*1024 + tid] = rec[gbase + k*1024 + tid];
  }
  __syncthreads();
  #define E1(s_, d_) { float4 r = u.e.sRec[(s_) - gbase]; int dl = (d_) - gbase; \
    int sb = __float_as_int(r.w); \
    atomicAdd(&u.e.sf[dl*4+0], r.y); atomicAdd(&u.e.sf[dl*4+1], r.x); \
    if (sb == nf) { atomicAdd(&u.e.sf[dl*4+2], r.y); atomicAdd(&u.e.sf[dl*4+3], r.x); } \
    else if (sb != 0) { int ix = atomicAdd(&mcnt[0], 1); \
      if (ix < MCAP) missL[ix] = make_int2(d_, s_); } }
  E1(S.x, D.x); E1(S.y, D.y); E1(S.z, D.z); E1(S.w, D.w);
  #undef E1
  __syncthreads();
  float4* sp = sums4 + (size_t)j*NTOT + gbase;
  #pragma unroll
  for (int k = 0; k < 4; k++) sp[4*tid + k] = sf4[4*tid + k];
}

// ---- encoder finish: acc -> relu -> mean-pool ----
__global__ void __launch_bounds__(256) k_enc_fin(
    const float4* __restrict__ rec, const float4* __restrict__ sums4,
    const float4* __restrict__ AC, const float* __restrict__ b2,
    const int* __restrict__ nfp, const int2* __restrict__ missL,
    const int* __restrict__ mcnt, float* __restrict__ hgsum)
{
  __shared__ float4 sS[TN];
  __shared__ float4 sRA[TN];
  __shared__ float red[256*4];
  int bid = blockIdx.x, g = bid & 63, part = bid >> 6;   // 1024 blocks
  int tid = threadIdx.x, lane = tid & 31, nrow = tid >> 5;
  int base = g*NNPG + part*TN;
  int nf = nfp[0];
  {
    int i = base + tid;
    sRA[tid] = rec[i];
    float4 a = sums4[0*NTOT + i], b = sums4[1*NTOT + i];
    float4 c = sums4[2*NTOT + i], d = sums4[3*NTOT + i];
    sS[tid] = make_float4(a.x+b.x+c.x+d.x, a.y+b.y+c.y+d.y,
                          a.z+b.z+c.z+d.z, a.w+b.w+c.w+d.w);
  }
  __syncthreads();
  const float4* q0 = AC + (size_t)lane*2;
  const float4* qn = AC + ((size_t)nf*32 + lane)*2;
  float4 A0 = q0[0], C0 = q0[1], An = qn[0], Cn = qn[1];
  float4 dA = make_float4(An.x-A0.x, An.y-A0.y, An.z-A0.z, An.w-A0.w);
  float4 dC = make_float4(Cn.x-C0.x, Cn.y-C0.y, Cn.z-C0.z, Cn.w-C0.w);
  float4 bb = ((const float4*)b2)[lane];
  int mc = mcnt[0]; mc = mc < MCAP ? mc : MCAP;
  float gx=0.f, gy=0.f, gz=0.f, gw=0.f;
  for (int it = 0; it < TN/8; ++it){
    int li = it*8 + nrow;
    int i = base + li;
    float4 rA = sRA[li];
    float4 s4 = sS[li];
    float accx = fmaf(s4.x,A0.x, fmaf(s4.z,dA.x, fmaf(s4.y,C0.x, s4.w*dC.x)));
    float accy = fmaf(s4.x,A0.y, fmaf(s4.z,dA.y, fmaf(s4.y,C0.y, s4.w*dC.y)));
    float accz = fmaf(s4.x,A0.z, fmaf(s4.z,dA.z, fmaf(s4.y,C0.z, s4.w*dC.z)));
    float accw = fmaf(s4.x,A0.w, fmaf(s4.z,dA.w, fmaf(s4.y,C0.w, s4.w*dC.w)));
    if (mc > 0){          // rare correctness path (off-{0,nf} source segments)
      for (int e = 0; e < mc; e++){
        int2 me = missL[e];
        if (me.x == i){
          float4 r = rec[me.y];
          int sb = __float_as_int(r.w);
          const float4* qm = AC + ((size_t)sb*32 + lane)*2;
          float4 qa = qm[0], qc = qm[1];
          accx = fmaf(r.y, qa.x-A0.x, fmaf(r.x, qc.x-C0.x, accx));
          accy = fmaf(r.y, qa.y-A0.y, fmaf(r.x, qc.y-C0.y, accy));
          accz = fmaf(r.y, qa.z-A0.z, fmaf(r.x, qc.z-C0.z, accz));
          accw = fmaf(r.y, qa.w-A0.w, fmaf(r.x, qc.w-C0.w, accw));
        }
      }
    }
    int si = __float_as_int(rA.w);
    bool m0 = (si == 0);
    float4 sa, sc;
    sa.x = m0 ? A0.x : An.x; sa.y = m0 ? A0.y : An.y; sa.z = m0 ? A0.z : An.z; sa.w = m0 ? A0.w : An.w;
    sc.x = m0 ? C0.x : Cn.x; sc.y = m0 ? C0.y : Cn.y; sc.z = m0 ? C0.z : Cn.z; sc.w = m0 ? C0.w : Cn.w;
    if (si != 0 && si != nf){
      const float4* qs = AC + ((size_t)si*32 + lane)*2;
      sa = qs[0]; sc = qs[1];
    }
    float d = rA.x, d2 = d*d, ca = rA.y*d;
    gx += fmaxf(fmaf(d, accx, fmaf(ca, sa.x, d2*sc.x)) + bb.x, 0.f);
    gy += fmaxf(fmaf(d, accy, fmaf(ca, sa.y, d2*sc.y)) + bb.y, 0.f);
    gz += fmaxf(fmaf(d, accz, fmaf(ca, sa.z, d2*sc.z)) + bb.z, 0.f);
    gw += fmaxf(fmaf(d, accw, fmaf(ca, sa.w, d2*sc.w)) + bb.w, 0.f);
  }
  __syncthreads();
  red[tid*4+0] = gx; red[tid*4+1] = gy; red[tid*4+2] = gz; red[tid*4+3] = gw;
  __syncthreads();
  if (nrow == 0){
    float tx=0.f, ty=0.f, tz=0.f, tw=0.f;
    for (int r2 = 0; r2 < 8; r2++){
      int t2 = (r2*32 + lane)*4;
      tx += red[t2]; ty += red[t2+1]; tz += red[t2+2]; tw += red[t2+3];
    }
    atomicAdd(&hgsum[g*HD + lane*4 + 0], tx);
    atomicAdd(&hgsum[g*HD + lane*4 + 1], ty);
    atomicAdd(&hgsum[g*HD + lane*4 + 2], tz);
    atomicAdd(&hgsum[g*HD + lane*4 + 3], tw);
  }
}

// ------- per-graph dense chain (slim, 128 thr) -------
__global__ void __launch_bounds__(128) k_small(
    const float* __restrict__ hgsum,
    const float* __restrict__ mu_w, const float* __restrict__ mu_b,
    const float* __restrict__ lv_w, const float* __restrict__ lv_b,
    const float* __restrict__ eps,
    const float* __restrict__ zn_w, const float* __restrict__ zn_b,
    const float* __restrict__ dec_w1, const float* __restrict__ dec_b1,
    float* __restrict__ out_mu, float* __restrict__ out_lv, float* __restrict__ out_z,
    float* __restrict__ t2, float* __restrict__ ushG, int* __restrict__ nf2)
{
  int g = blockIdx.x, tid = threadIdx.x;
  __shared__ float hg[128], zsh[64], znsh[128];
  __shared__ int ks[128];
  hg[tid] = hgsum[g*HD + tid] * (1.0f/4096.0f);
  __syncthreads();
  if (tid < 64){
    int l = tid;
    float m = mu_b[l], v = lv_b[l];
    for (int k = 0; k < HD; k++){
      float hv = hg[k];
      m = fmaf(hv, mu_w[k*LD + l], m);
      v = fmaf(hv, lv_w[k*LD + l], v);
    }
    int o = g*LD + l;
    out_mu[o] = m; out_lv[o] = v;
    float zv = fmaf(expf(0.5f*v), eps[o], m);
    out_z[o] = zv; zsh[l] = zv;
  }
  __syncthreads();
  {
    int k = tid;
    float acc = zn_b[k];
    for (int l = 0; l < LD; l++) acc = fmaf(zsh[l], zn_w[l*HD + k], acc);
    znsh[k] = acc;
  }
  __syncthreads();
  float w;
  {
    int k = tid;
    float acc = 0.f;
    for (int j = 0; j < HD; j++) acc = fmaf(znsh[j], dec_w1[j*HD + k], acc);
    ushG[g*HD + k] = acc;
    w = acc;
  }
  float b = dec_b1[tid];
  float t; int kind;
  if (w != 0.0f){ t = -b / w; kind = (w > 0.0f) ? 0 : 1; }
  else          { t = INFINITY; kind = 2; }
  t2[g*HD + tid] = t; ks[tid] = kind;
  __syncthreads();
  if (tid == 0){
    int c = 0;
    for (int q = 0; q < 128; q++) c += (ks[q] != 2) ? 1 : 0;
    nf2[g] = c;
  }
}

// segD per node -> rec.y (coalesced float4 RMW) + used bitmap
__global__ void k_seg2(const float* __restrict__ t2, const float* __restrict__ srowA,
                       float4* __restrict__ rec, int* __restrict__ segUsed){
  __shared__ float ts[128];
  __shared__ int used[8];
  int tid = threadIdx.x;
  int i = blockIdx.x*256 + tid;
  int g = blockIdx.x >> 4;
  if (tid < 128) ts[tid] = t2[g*HD + tid];
  if (tid < 8) used[tid] = 0;
  __syncthreads();
  float a = srowA[i];
  int sc = 0;
  for (int q = 0; q < 128; q++) sc += (ts[q] < a) ? 1 : 0;
  float4 r = rec[i];
  r.y = __int_as_float(sc);
  rec[i] = r;
  atomicOr(&used[sc>>5], 1u << (sc & 31));
  __syncthreads();
  if (tid < 8 && used[tid]) atomicOr(&segUsed[g*8 + tid], used[tid]);
}

// ---- edge pass 2 (decoder) + tabrows-dec riders (blocks 256..319) ----
__global__ void __launch_bounds__(1024) k_edge2dec(
    const int* __restrict__ ei, const float4* __restrict__ rec,
    const int* __restrict__ nf2, float4* __restrict__ sums4,
    int2* __restrict__ missL, int* __restrict__ mcnt,
    const float* __restrict__ ushG, const float* __restrict__ dec_b1,
    const float* __restrict__ dec_w2, const int* __restrict__ segU,
    float* __restrict__ AC2)
{
  __shared__ union {
    struct { float sf[NNPG*4]; float4 sRec[NNPG]; } e;            // 128 KB
    struct { float ws[128], bs[128], tsh[128];
             int ks[128], rr[128]; float red[8][128][4]; } t;     // ~19 KB
  } u;
  int tid = threadIdx.x;
  if (blockIdx.x >= 256){
    tabrows_body(blockIdx.x - 256, tid, ushG, dec_b1, dec_w2, segU, nf2, AC2,
                 u.t.ws, u.t.bs, u.t.tsh, u.t.ks, u.t.rr, u.t.red);
    return;
  }
  int g, j; swz(blockIdx.x, g, j);
  int gbase = g*NNPG;
  int nf = nf2[g];
  const int4* srcs4 = (const int4*)(ei + g*EPG + j*EPB);
  const int4* dsts4 = (const int4*)(ei + ET + g*EPG + j*EPB);
  int4 S = srcs4[tid], D = dsts4[tid];
  float4* sf4 = (float4*)u.e.sf;
  #pragma unroll
  for (int k = 0; k < 4; k++){
    sf4[4*tid + k] = make_float4(0.f,0.f,0.f,0.f);
    u.e.sRec[k*1024 + tid] = rec[gbase + k*1024 + tid];
  }
  __syncthreads();
  #define E2(s_, d_) { float4 r = u.e.sRec[(s_) - gbase]; int dl = (d_) - gbase; \
    int sb = __float_as_int(r.y); \
    atomicAdd(&u.e.sf[dl*4+0], r.z); atomicAdd(&u.e.sf[dl*4+1], r.x); \
    if (sb == nf) { atomicAdd(&u.e.sf[dl*4+2], r.z); atomicAdd(&u.e.sf[dl*4+3], r.x); } \
    else if (sb != 0) { int ix = atomicAdd(&mcnt[1], 1); \
      if (ix < MCAP) missL[ix] = make_int2(d_, s_); } }
  E2(S.x, D.x); E2(S.y, D.y); E2(S.z, D.z); E2(S.w, D.w);
  #undef E2
  __syncthreads();
  float4* sp = sums4 + (size_t)j*NTOT + gbase;
  #pragma unroll
  for (int k = 0; k < 4; k++) sp[4*tid + k] = sf4[4*tid + k];
}

// ---- decoder finish: acc -> relu -> out-proj -> tanh ----
__global__ void __launch_bounds__(256) k_dec_fin(
    const float4* __restrict__ rec, const float4* __restrict__ sums4,
    const float4* __restrict__ AC2, const float* __restrict__ b2,
    const float* __restrict__ ow, const float* __restrict__ ob,
    const int* __restrict__ nf2, const int2* __restrict__ missL,
    const int* __restrict__ mcnt, float* __restrict__ recon)
{
  __shared__ float4 sS[TN];
  __shared__ float4 sRA[TN];
  int bid = blockIdx.x, g = bid & 63, part = bid >> 6;
  int tid = threadIdx.x, lane = tid & 31, nrow = tid >> 5;
  int base = g*NNPG + part*TN;
  int nf = nf2[g];
  const float4* AC = AC2 + (size_t)g*NSEG*64;
  {
    int i = base + tid;
    sRA[tid] = rec[i];
    float4 a = sums4[0*NTOT + i], b = sums4[1*NTOT + i];
    float4 c = sums4[2*NTOT + i], d = sums4[3*NTOT + i];
    sS[tid] = make_float4(a.x+b.x+c.x+d.x, a.y+b.y+c.y+d.y,
                          a.z+b.z+c.z+d.z, a.w+b.w+c.w+d.w);
  }
  __syncthreads();
  const float4* q0 = AC + (size_t)lane*2;
  const float4* qn = AC + ((size_t)nf*32 + lane)*2;
  float4 A0 = q0[0], C0 = q0[1], An = qn[0], Cn = qn[1];
  float4 dA = make_float4(An.x-A0.x, An.y-A0.y, An.z-A0.z, An.w-A0.w);
  float4 dC = make_float4(Cn.x-C0.x, Cn.y-C0.y, Cn.z-C0.z, Cn.w-C0.w);
  float4 bb  = ((const float4*)b2)[lane];
  float4 owv = ((const float4*)ow)[lane];
  float obv = ob[0];
  int mc = mcnt[1]; mc = mc < MCAP ? mc : MCAP;
  for (int it = 0; it < TN/8; ++it){
    int li = it*8 + nrow;
    int i = base + li;
    float4 rA = sRA[li];
    float4 s4 = sS[li];
    float accx = fmaf(s4.x,A0.x, fmaf(s4.z,dA.x, fmaf(s4.y,C0.x, s4.w*dC.x)));
    float accy = fmaf(s4.x,A0.y, fmaf(s4.z,dA.y, fmaf(s4.y,C0.y, s4.w*dC.y)));
    float accz = fmaf(s4.x,A0.z, fmaf(s4.z,dA.z, fmaf(s4.y,C0.z, s4.w*dC.z)));
    float accw = fmaf(s4.x,A0.w, fmaf(s4.z,dA.w, fmaf(s4.y,C0.w, s4.w*dC.w)));
    if (mc > 0){
      for (int e = 0; e < mc; e++){
        int2 me = missL[e];
        if (me.x == i){
          float4 r = rec[me.y];
          int sb = __float_as_int(r.y);
          const float4* qm = AC + ((size_t)sb*32 + lane)*2;
          float4 qa = qm[0], qc = qm[1];
          accx = fmaf(r.z, qa.x-A0.x, fmaf(r.x, qc.x-C0.x, accx));
          accy = fmaf(r.z, qa.y-A0.y, fmaf(r.x, qc.y-C0.y, accy));
          accz = fmaf(r.z, qa.z-A0.z, fmaf(r.x, qc.z-C0.z, accz));
          accw = fmaf(r.z, qa.w-A0.w, fmaf(r.x, qc.w-C0.w, accw));
        }
      }
    }
    int si = __float_as_int(rA.y);
    bool m0 = (si == 0);
    float4 sa, sc;
    sa.x = m0 ? A0.x : An.x; sa.y = m0 ? A0.y : An.y; sa.z = m0 ? A0.z : An.z; sa.w = m0 ? A0.w : An.w;
    sc.x = m0 ? C0.x : Cn.x; sc.y = m0 ? C0.y : Cn.y; sc.z = m0 ? C0.z : Cn.z; sc.w = m0 ? C0.w : Cn.w;
    if (si != 0 && si != nf){
      const float4* qs = AC + ((size_t)si*32 + lane)*2;
      sa = qs[0]; sc = qs[1];
    }
    float d = rA.x, d2 = d*d, ca = rA.z*d;
    float hx = fmaxf(fmaf(d, accx, fmaf(ca, sa.x, d2*sc.x)) + bb.x, 0.f);
    float hy = fmaxf(fmaf(d, accy, fmaf(ca, sa.y, d2*sc.y)) + bb.y, 0.f);
    float hz = fmaxf(fmaf(d, accz, fmaf(ca, sa.z, d2*sc.z)) + bb.z, 0.f);
    float hw = fmaxf(fmaf(d, accw, fmaf(ca, sa.w, d2*sc.w)) + bb.w, 0.f);
    float dsum = hx*owv.x + hy*owv.y + hz*owv.z + hw*owv.w;
    for (int o2 = 16; o2 > 0; o2 >>= 1) dsum += __shfl_down(dsum, o2, 32);
    if (lane == 0) recon[i] = tanhf(dsum + obv);
  }
}

// ---------------- launch ----------------
extern "C" void kernel_launch(void* const* d_in, const int* in_sizes, int n_in,
                              void* d_out, int out_size, void* d_ws, size_t ws_size,
                              hipStream_t stream){
  (void)in_sizes; (void)n_in; (void)out_size; (void)ws_size;
  const float* x      = (const float*)d_in[0];
  const float* eps    = (const float*)d_in[1];
  const float* enc_w1 = (const float*)d_in[2];
  const float* enc_b1 = (const float*)d_in[3];
  const float* enc_w2 = (const float*)d_in[4];
  const float* enc_b2 = (const float*)d_in[5];
  const float* mu_w   = (const float*)d_in[6];
  const float* mu_b   = (const float*)d_in[7];
  const float* lv_w   = (const float*)d_in[8];
  const float* lv_b   = (const float*)d_in[9];
  const float* zn_w   = (const float*)d_in[10];
  const float* zn_b   = (const float*)d_in[11];
  const float* dec_w1 = (const float*)d_in[12];
  const float* dec_b1 = (const float*)d_in[13];
  const float* dec_w2 = (const float*)d_in[14];
  const float* dec_b2 = (const float*)d_in[15];
  const float* out_w  = (const float*)d_in[16];
  const float* out_b  = (const float*)d_in[17];
  const int*   ei     = (const int*)d_in[18];

  float* out       = (float*)d_out;
  float* out_recon = out;
  float* out_mu    = out + NTOT;
  float* out_lv    = out_mu + BG*LD;
  float* out_z     = out_lv + BG*LD;

  char* w = (char*)d_ws;
  size_t off_b = 0;
  auto alloc = [&](size_t bytes)->void*{
    void* p = w + off_b;
    off_b += (bytes + 255) & ~(size_t)255;
    return p;
  };
  // region A (16MB): cntJ[0:4M) + accJ[4M:12M) early; sums4[0:16M) later
  char*   regA   = (char*) alloc((size_t)4*NTOT*16);
  int*    cntJ   = (int*)   regA;
  float2* accJ   = (float2*)(regA + (size_t)4*NTOT*4);
  float4* sums4  = (float4*)regA;
  float2* xd     = (float2*)alloc((size_t)NTOT*8);
  float4* rec    = (float4*)alloc((size_t)NTOT*16);
  float*  srowA  = (float*) alloc((size_t)NTOT*4);
  int2*   missL  = (int2*)  alloc((size_t)MCAP*8);
  float*  t1     = (float*) alloc(128*4);
  int*    nf1    = (int*)   alloc(256);
  int*    nf2    = (int*)   alloc(BG*4);
  int*    segU1  = (int*)   alloc(8*4);
  int*    segU   = (int*)   alloc(BG*8*4);
  float*  t2     = (float*) alloc((size_t)BG*HD*4);
  float*  ushG   = (float*) alloc((size_t)BG*HD*4);
  float*  AC1    = (float*) alloc((size_t)NSEG*256*4);
  float*  AC2    = (float*) alloc((size_t)BG*NSEG*256*4);
  float*  hgsum  = (float*) alloc((size_t)BG*HD*4);
  int*    mcnt   = (int*)   alloc(256);

  // 9 dispatches; zeroing folded into k_count's rider block

  k_count <<<257, 1024, 0, stream>>>(ei, enc_w1, enc_b1, cntJ, t1, nf1,
                                     hgsum, mcnt, segU1, segU);
  k_edge1 <<<256, 1024, 0, stream>>>(ei, cntJ, x, xd, accJ);
  k_pack  <<<NTOT/256, 256, 0, stream>>>(xd, accJ, t1, rec, srowA, segU1);

  k_edge2enc<<<257, 1024, 0, stream>>>(ei, rec, nf1, sums4, missL, mcnt,
                                       enc_w1, enc_b1, enc_w2, segU1, AC1);
  k_enc_fin <<<1024, 256, 0, stream>>>(rec, sums4, (const float4*)AC1, enc_b2,
                                       nf1, missL, mcnt, hgsum);

  k_small<<<BG, 128, 0, stream>>>(hgsum, mu_w, mu_b, lv_w, lv_b, eps,
                                  zn_w, zn_b, dec_w1, dec_b1,
                                  out_mu, out_lv, out_z, t2, ushG, nf2);

  k_seg2<<<NTOT/256, 256, 0, stream>>>(t2, srowA, rec, segU);

  k_edge2dec<<<320, 1024, 0, stream>>>(ei, rec, nf2, sums4, missL, mcnt,
                                       ushG, dec_b1, dec_w2, segU, AC2);
  k_dec_fin <<<1024, 256, 0, stream>>>(rec, sums4, (const float4*)AC2, dec_b2,
                                       out_w, out_b, nf2, missL, mcnt, out_recon);
}

// Round 19
// 166.896 us; speedup vs baseline: 1.0887x; 1.0887x over previous
//
#include <hip/hip_runtime.h>
#include <math.h>

#define NTOT 262144   // total nodes
#define BG   64       // graphs
#define NNPG 4096     // nodes per graph
#define ET   1048576  // directed edges
#define EPG  16384    // edges per graph
#define EPB  4096     // edges per sub-block (4 sub-blocks/graph)
#define HD   128
#define LD   64
#define NSEG 129
#define TN   256
#define MCAP ET       // miss-list capacity (int2 entries)

// XCD-bijective swizzle: all 4 sub-blocks of graph g share (b&7) -> one XCD L2
__device__ __forceinline__ void swz(int b, int& g, int& j){
  int xcd = b & 7, q = b >> 3;
  g = (q >> 2)*8 + xcd;
  j = q & 3;
}

// ---- count: LDS histogram per sub-block -> planar cntJ; block 256 = rider:
//      tab1a (t1,nf1) + zero hgsum/mcnt/segU1/segU (replaces all memsets) ----
__global__ void __launch_bounds__(1024) k_count(const int* __restrict__ ei,
                                                const float* __restrict__ w1,
                                                const float* __restrict__ b1,
                                                int* __restrict__ cntJ,
                                                float* __restrict__ t1, int* __restrict__ nfp,
                                                float* __restrict__ hgsum,
                                                int* __restrict__ mcnt,
                                                int* __restrict__ segU1,
                                                int* __restrict__ segU){
  __shared__ int h[NNPG];
  int tid = threadIdx.x;
  if (blockIdx.x == 256){
    for (int idx = tid; idx < BG*HD; idx += 1024) hgsum[idx] = 0.f;
    if (tid < 2) mcnt[tid] = 0;
    if (tid < 8) segU1[tid] = 0;
    if (tid < BG*8) segU[tid] = 0;
    if (tid < 128){
      float w = w1[tid], b = b1[tid];
      float t; int kind;
      if (w != 0.0f){ t = -b / w; kind = (w > 0.0f) ? 0 : 1; }
      else          { t = INFINITY; kind = 2; }
      h[tid] = kind;
      t1[tid] = t;
    }
    __syncthreads();
    if (tid == 0){
      int c = 0;
      for (int q = 0; q < 128; q++) c += (h[q] != 2) ? 1 : 0;
      nfp[0] = c;
    }
    return;
  }
  int g, j; swz(blockIdx.x, g, j);
  #pragma unroll
  for (int k = tid; k < NNPG; k += 1024) h[k] = 0;
  __syncthreads();
  int gbase = g*NNPG;
  const int4* dsts4 = (const int4*)(ei + ET + g*EPG + j*EPB);
  int4 D = dsts4[tid];
  atomicAdd(&h[D.x - gbase], 1); atomicAdd(&h[D.y - gbase], 1);
  atomicAdd(&h[D.z - gbase], 1); atomicAdd(&h[D.w - gbase], 1);
  __syncthreads();
  int* plane = cntJ + j*NTOT + gbase;
  #pragma unroll
  for (int k = tid; k < NNPG; k += 1024) plane[k] = h[k];
}

// ---- edge pass 1 (fused dinv/xd): per-dest sums of (d_s*x_s, d_s) ----
// Each block computes its graph's xd into LDS; sub-block 0 also writes it out.
__global__ void __launch_bounds__(1024) k_edge1(
    const int* __restrict__ ei, const int* __restrict__ cntJ,
    const float* __restrict__ x, float2* __restrict__ xd,
    float2* __restrict__ accJ)
{
  __shared__ float2 sxd[NNPG];    // 32 KB
  __shared__ float ax[NNPG];      // 16 KB
  __shared__ float s1[NNPG];      // 16 KB
  int tid = threadIdx.x;
  int g, j; swz(blockIdx.x, g, j);
  int gbase = g*NNPG;
  const int4* srcs4 = (const int4*)(ei + g*EPG + j*EPB);
  const int4* dsts4 = (const int4*)(ei + ET + g*EPG + j*EPB);
  int4 S = srcs4[tid], D = dsts4[tid];
  {
    int i0 = 4*tid;
    int4 c0 = *(const int4*)(cntJ + 0*NTOT + gbase + i0);
    int4 c1 = *(const int4*)(cntJ + 1*NTOT + gbase + i0);
    int4 c2 = *(const int4*)(cntJ + 2*NTOT + gbase + i0);
    int4 c3 = *(const int4*)(cntJ + 3*NTOT + gbase + i0);
    float4 xv = *(const float4*)(x + gbase + i0);
    float2 p0 = make_float2(xv.x, rsqrtf((float)(c0.x+c1.x+c2.x+c3.x) + 1.0f));
    float2 p1 = make_float2(xv.y, rsqrtf((float)(c0.y+c1.y+c2.y+c3.y) + 1.0f));
    float2 p2 = make_float2(xv.z, rsqrtf((float)(c0.z+c1.z+c2.z+c3.z) + 1.0f));
    float2 p3 = make_float2(xv.w, rsqrtf((float)(c0.w+c1.w+c2.w+c3.w) + 1.0f));
    sxd[i0+0] = p0; sxd[i0+1] = p1; sxd[i0+2] = p2; sxd[i0+3] = p3;
    if (j == 0){
      float4* xd4 = (float4*)(xd + gbase);
      xd4[2*tid+0] = make_float4(p0.x, p0.y, p1.x, p1.y);
      xd4[2*tid+1] = make_float4(p2.x, p2.y, p3.x, p3.y);
    }
    *(float4*)(ax + i0) = make_float4(0.f,0.f,0.f,0.f);
    *(float4*)(s1 + i0) = make_float4(0.f,0.f,0.f,0.f);
  }
  __syncthreads();
  #define P1(s_, d_) { float2 sd = sxd[(s_) - gbase]; int dl = (d_) - gbase; \
    atomicAdd(&ax[dl], sd.y * sd.x); \
    atomicAdd(&s1[dl], sd.y); }
  P1(S.x, D.x); P1(S.y, D.y); P1(S.z, D.z); P1(S.w, D.w);
  #undef P1
  __syncthreads();
  float4* ap = (float4*)(accJ + (size_t)j*NTOT + gbase);
  ap[2*tid+0] = make_float4(ax[4*tid+0], s1[4*tid+0], ax[4*tid+1], s1[4*tid+1]);
  ap[2*tid+1] = make_float4(ax[4*tid+2], s1[4*tid+2], ax[4*tid+3], s1[4*tid+3]);
}

// ---- pack per-node record: rec[i] = (d, d*ax, d*srow, segE) + segE bitmap ----
__global__ void k_pack(const float2* __restrict__ xd, const float2* __restrict__ accJ,
                       const float* __restrict__ t1,
                       float4* __restrict__ rec, float* __restrict__ srowA,
                       int* __restrict__ segU1){
  __shared__ float ts[128];
  __shared__ int used[8];
  int tid = threadIdx.x;
  if (tid < 128) ts[tid] = t1[tid];
  if (tid < 8) used[tid] = 0;
  __syncthreads();
  int i = blockIdx.x*256 + tid;
  float2 xdv = xd[i];
  float2 a0 = accJ[0*NTOT + i], a1 = accJ[1*NTOT + i];
  float2 a2 = accJ[2*NTOT + i], a3 = accJ[3*NTOT + i];
  float axs = (a0.x + a1.x) + (a2.x + a3.x);
  float s1s = (a0.y + a1.y) + (a2.y + a3.y);
  float di = xdv.y;
  float ax = di * (di * xdv.x + axs);
  float sr = di * (di + s1s);
  int sc = 0;
  for (int q = 0; q < 128; q++) sc += (ts[q] < ax) ? 1 : 0;
  rec[i] = make_float4(di, di*ax, di*sr, __int_as_float(sc));
  srowA[i] = sr;
  atomicOr(&used[sc>>5], 1u << (sc & 31));
  __syncthreads();
  if (tid < 8 && used[tid]) atomicOr(&segU1[tid], used[tid]);
}

// ---- table rows builder (high-occupancy): rows {0, nf} via q-split partials,
// plus any extra USED rows (rare fallback). 1024 thr = 8 qgroups x 128 k.
__global__ void __launch_bounds__(1024) k_tabrows(
    const float* __restrict__ wsrc, const float* __restrict__ bsrc,
    const float* __restrict__ w2, const int* __restrict__ segUsed,
    const int* __restrict__ nfA, float* __restrict__ ACbase)
{
  __shared__ float ws[128], bs[128], tsh[128];
  __shared__ int ks[128], rr[128];
  __shared__ float red[8][128][4];
  int g = blockIdx.x;
  int tid = threadIdx.x;
  int k = tid & 127, qg = tid >> 7;
  if (qg == 0){
    float w = wsrc[g*HD + k], b = bsrc[k];
    float t; int kind;
    if (w != 0.0f){ t = -b / w; kind = (w > 0.0f) ? 0 : 1; }
    else          { t = INFINITY; kind = 2; }
    ws[k] = w; bs[k] = b; tsh[k] = t; ks[k] = kind;
  }
  __syncthreads();
  if (qg == 0){          // ranks (needed only for rare extra rows)
    float t = tsh[k];
    int r = 0;
    for (int q = 0; q < 128; q++){
      if (ks[q] != 2){
        float tq = tsh[q];
        if (tq < t || (tq == t && q < k)) r++;
      }
    }
    rr[k] = r;
  }
  // rows 0 and nf: masks depend only on kind/bias
  float a0=0.f, c0=0.f, an=0.f, cn=0.f;
  #pragma unroll
  for (int u = 0; u < 16; u++){
    int q = qg*16 + u;
    float v = w2[q*HD + k];
    int kd = ks[q];
    float wq = ws[q], bq = bs[q];
    bool m0 = (kd == 1) || (kd == 2 && bq > 0.f);
    bool mn = (kd == 0) || (kd == 2 && bq > 0.f);
    float wv = wq*v, bv = bq*v;
    a0 += m0 ? wv : 0.f; c0 += m0 ? bv : 0.f;
    an += mn ? wv : 0.f; cn += mn ? bv : 0.f;
  }
  red[qg][k][0]=a0; red[qg][k][1]=c0; red[qg][k][2]=an; red[qg][k][3]=cn;
  __syncthreads();
  int nf = nfA[g];
  float* ACg = ACbase + (size_t)g*NSEG*256;
  int base = (k>>2)*8 + (k&3);
  if (qg == 0){
    float A0=0.f,C0=0.f,An=0.f,Cn=0.f;
    #pragma unroll
    for (int p = 0; p < 8; p++){
      A0+=red[p][k][0]; C0+=red[p][k][1]; An+=red[p][k][2]; Cn+=red[p][k][3];
    }
    ACg[base] = A0; ACg[base+4] = C0;
    ACg[(size_t)nf*256 + base] = An; ACg[(size_t)nf*256 + base + 4] = Cn;
  }
  __syncthreads();
  // extra used rows beyond {0, nf} (rare): full rank-based mask, q-split
  for (int wd = 0; wd < 5; wd++){
    unsigned m = (unsigned)segUsed[g*8 + wd];
    if (wd == 0) m &= ~1u;
    if ((nf >> 5) == wd) m &= ~(1u << (nf & 31));
    while (m){
      int bit = __ffs(m) - 1;
      m &= m - 1;
      int s = wd*32 + bit;
      float pa=0.f, pc=0.f;
      #pragma unroll
      for (int u = 0; u < 16; u++){
        int q = qg*16 + u;
        int kd = ks[q];
        bool act = (kd == 0) ? (rr[q] < s) : (kd == 1) ? (rr[q] >= s) : (bs[q] > 0.f);
        float v = act ? w2[q*HD + k] : 0.f;
        pa = fmaf(ws[q], v, pa); pc = fmaf(bs[q], v, pc);
      }
      red[qg][k][0]=pa; red[qg][k][1]=pc;
      __syncthreads();
      if (qg == 0){
        float A=0.f,C=0.f;
        #pragma unroll
        for (int p = 0; p < 8; p++){ A+=red[p][k][0]; C+=red[p][k][1]; }
        ACg[(size_t)s*256 + base] = A; ACg[(size_t)s*256 + base + 4] = C;
      }
      __syncthreads();
    }
  }
}

// ---- edge pass 2 (encoder): rec slab staged in LDS; per-dest 4 sums ----
__global__ void __launch_bounds__(1024) k_edge2enc(
    const int* __restrict__ ei, const float4* __restrict__ rec,
    const int* __restrict__ nfp, float4* __restrict__ sums4,
    int2* __restrict__ missL, int* __restrict__ mcnt)
{
  __shared__ float sf[NNPG*4];     // 64 KB
  __shared__ float4 sRec[NNPG];    // 64 KB
  int g, j; swz(blockIdx.x, g, j);
  int tid = threadIdx.x;
  int gbase = g*NNPG;
  int nf = nfp[0];
  const int4* srcs4 = (const int4*)(ei + g*EPG + j*EPB);
  const int4* dsts4 = (const int4*)(ei + ET + g*EPG + j*EPB);
  int4 S = srcs4[tid], D = dsts4[tid];
  float4* sf4 = (float4*)sf;
  #pragma unroll
  for (int k = 0; k < 4; k++){
    sf4[4*tid + k] = make_float4(0.f,0.f,0.f,0.f);
    sRec[k*1024 + tid] = rec[gbase + k*1024 + tid];
  }
  __syncthreads();
  #define E1(s_, d_) { float4 r = sRec[(s_) - gbase]; int dl = (d_) - gbase; \
    int sb = __float_as_int(r.w); \
    atomicAdd(&sf[dl*4+0], r.y); atomicAdd(&sf[dl*4+1], r.x); \
    if (sb == nf) { atomicAdd(&sf[dl*4+2], r.y); atomicAdd(&sf[dl*4+3], r.x); } \
    else if (sb != 0) { int ix = atomicAdd(&mcnt[0], 1); \
      if (ix < MCAP) missL[ix] = make_int2(d_, s_); } }
  E1(S.x, D.x); E1(S.y, D.y); E1(S.z, D.z); E1(S.w, D.w);
  #undef E1
  __syncthreads();
  float4* sp = sums4 + (size_t)j*NTOT + gbase;
  #pragma unroll
  for (int k = 0; k < 4; k++) sp[4*tid + k] = sf4[4*tid + k];
}

// ---- encoder finish: acc -> relu -> mean-pool ----
__global__ void __launch_bounds__(256) k_enc_fin(
    const float4* __restrict__ rec, const float4* __restrict__ sums4,
    const float4* __restrict__ AC, const float* __restrict__ b2,
    const int* __restrict__ nfp, const int2* __restrict__ missL,
    const int* __restrict__ mcnt, float* __restrict__ hgsum)
{
  __shared__ float4 sS[TN];
  __shared__ float4 sRA[TN];
  __shared__ float red[256*4];
  int bid = blockIdx.x, g = bid & 63, part = bid >> 6;   // 1024 blocks
  int tid = threadIdx.x, lane = tid & 31, nrow = tid >> 5;
  int base = g*NNPG + part*TN;
  int nf = nfp[0];
  {
    int i = base + tid;
    sRA[tid] = rec[i];
    float4 a = sums4[0*NTOT + i], b = sums4[1*NTOT + i];
    float4 c = sums4[2*NTOT + i], d = sums4[3*NTOT + i];
    sS[tid] = make_float4(a.x+b.x+c.x+d.x, a.y+b.y+c.y+d.y,
                          a.z+b.z+c.z+d.z, a.w+b.w+c.w+d.w);
  }
  __syncthreads();
  const float4* q0 = AC + (size_t)lane*2;
  const float4* qn = AC + ((size_t)nf*32 + lane)*2;
  float4 A0 = q0[0], C0 = q0[1], An = qn[0], Cn = qn[1];
  float4 dA = make_float4(An.x-A0.x, An.y-A0.y, An.z-A0.z, An.w-A0.w);
  float4 dC = make_float4(Cn.x-C0.x, Cn.y-C0.y, Cn.z-C0.z, Cn.w-C0.w);
  float4 bb = ((const float4*)b2)[lane];
  int mc = mcnt[0]; mc = mc < MCAP ? mc : MCAP;
  float gx=0.f, gy=0.f, gz=0.f, gw=0.f;
  for (int it = 0; it < TN/8; ++it){
    int li = it*8 + nrow;
    int i = base + li;
    float4 rA = sRA[li];
    float4 s4 = sS[li];
    float accx = fmaf(s4.x,A0.x, fmaf(s4.z,dA.x, fmaf(s4.y,C0.x, s4.w*dC.x)));
    float accy = fmaf(s4.x,A0.y, fmaf(s4.z,dA.y, fmaf(s4.y,C0.y, s4.w*dC.y)));
    float accz = fmaf(s4.x,A0.z, fmaf(s4.z,dA.z, fmaf(s4.y,C0.z, s4.w*dC.z)));
    float accw = fmaf(s4.x,A0.w, fmaf(s4.z,dA.w, fmaf(s4.y,C0.w, s4.w*dC.w)));
    if (mc > 0){          // rare correctness path (off-{0,nf} source segments)
      for (int e = 0; e < mc; e++){
        int2 me = missL[e];
        if (me.x == i){
          float4 r = rec[me.y];
          int sb = __float_as_int(r.w);
          const float4* qm = AC + ((size_t)sb*32 + lane)*2;
          float4 qa = qm[0], qc = qm[1];
          accx = fmaf(r.y, qa.x-A0.x, fmaf(r.x, qc.x-C0.x, accx));
          accy = fmaf(r.y, qa.y-A0.y, fmaf(r.x, qc.y-C0.y, accy));
          accz = fmaf(r.y, qa.z-A0.z, fmaf(r.x, qc.z-C0.z, accz));
          accw = fmaf(r.y, qa.w-A0.w, fmaf(r.x, qc.w-C0.w, accw));
        }
      }
    }
    int si = __float_as_int(rA.w);
    bool m0 = (si == 0);
    float4 sa, sc;
    sa.x = m0 ? A0.x : An.x; sa.y = m0 ? A0.y : An.y; sa.z = m0 ? A0.z : An.z; sa.w = m0 ? A0.w : An.w;
    sc.x = m0 ? C0.x : Cn.x; sc.y = m0 ? C0.y : Cn.y; sc.z = m0 ? C0.z : Cn.z; sc.w = m0 ? C0.w : Cn.w;
    if (si != 0 && si != nf){
      const float4* qs = AC + ((size_t)si*32 + lane)*2;
      sa = qs[0]; sc = qs[1];
    }
    float d = rA.x, d2 = d*d, ca = rA.y*d;
    gx += fmaxf(fmaf(d, accx, fmaf(ca, sa.x, d2*sc.x)) + bb.x, 0.f);
    gy += fmaxf(fmaf(d, accy, fmaf(ca, sa.y, d2*sc.y)) + bb.y, 0.f);
    gz += fmaxf(fmaf(d, accz, fmaf(ca, sa.z, d2*sc.z)) + bb.z, 0.f);
    gw += fmaxf(fmaf(d, accw, fmaf(ca, sa.w, d2*sc.w)) + bb.w, 0.f);
  }
  __syncthreads();
  red[tid*4+0] = gx; red[tid*4+1] = gy; red[tid*4+2] = gz; red[tid*4+3] = gw;
  __syncthreads();
  if (nrow == 0){
    float tx=0.f, ty=0.f, tz=0.f, tw=0.f;
    for (int r2 = 0; r2 < 8; r2++){
      int t2 = (r2*32 + lane)*4;
      tx += red[t2]; ty += red[t2+1]; tz += red[t2+2]; tw += red[t2+3];
    }
    atomicAdd(&hgsum[g*HD + lane*4 + 0], tx);
    atomicAdd(&hgsum[g*HD + lane*4 + 1], ty);
    atomicAdd(&hgsum[g*HD + lane*4 + 2], tz);
    atomicAdd(&hgsum[g*HD + lane*4 + 3], tw);
  }
}

// ------- per-graph dense chain (slim, 128 thr) -------
__global__ void __launch_bounds__(128) k_small(
    const float* __restrict__ hgsum,
    const float* __restrict__ mu_w, const float* __restrict__ mu_b,
    const float* __restrict__ lv_w, const float* __restrict__ lv_b,
    const float* __restrict__ eps,
    const float* __restrict__ zn_w, const float* __restrict__ zn_b,
    const float* __restrict__ dec_w1, const float* __restrict__ dec_b1,
    float* __restrict__ out_mu, float* __restrict__ out_lv, float* __restrict__ out_z,
    float* __restrict__ t2, float* __restrict__ ushG, int* __restrict__ nf2)
{
  int g = blockIdx.x, tid = threadIdx.x;
  __shared__ float hg[128], zsh[64], znsh[128];
  __shared__ int ks[128];
  hg[tid] = hgsum[g*HD + tid] * (1.0f/4096.0f);
  __syncthreads();
  if (tid < 64){
    int l = tid;
    float m = mu_b[l], v = lv_b[l];
    for (int k = 0; k < HD; k++){
      float hv = hg[k];
      m = fmaf(hv, mu_w[k*LD + l], m);
      v = fmaf(hv, lv_w[k*LD + l], v);
    }
    int o = g*LD + l;
    out_mu[o] = m; out_lv[o] = v;
    float zv = fmaf(expf(0.5f*v), eps[o], m);
    out_z[o] = zv; zsh[l] = zv;
  }
  __syncthreads();
  {
    int k = tid;
    float acc = zn_b[k];
    for (int l = 0; l < LD; l++) acc = fmaf(zsh[l], zn_w[l*HD + k], acc);
    znsh[k] = acc;
  }
  __syncthreads();
  float w;
  {
    int k = tid;
    float acc = 0.f;
    for (int j = 0; j < HD; j++) acc = fmaf(znsh[j], dec_w1[j*HD + k], acc);
    ushG[g*HD + k] = acc;
    w = acc;
  }
  float b = dec_b1[tid];
  float t; int kind;
  if (w != 0.0f){ t = -b / w; kind = (w > 0.0f) ? 0 : 1; }
  else          { t = INFINITY; kind = 2; }
  t2[g*HD + tid] = t; ks[tid] = kind;
  __syncthreads();
  if (tid == 0){
    int c = 0;
    for (int q = 0; q < 128; q++) c += (ks[q] != 2) ? 1 : 0;
    nf2[g] = c;
  }
}

// segD per node -> rec.y (coalesced float4 RMW) + used bitmap
__global__ void k_seg2(const float* __restrict__ t2, const float* __restrict__ srowA,
                       float4* __restrict__ rec, int* __restrict__ segUsed){
  __shared__ float ts[128];
  __shared__ int used[8];
  int tid = threadIdx.x;
  int i = blockIdx.x*256 + tid;
  int g = blockIdx.x >> 4;
  if (tid < 128) ts[tid] = t2[g*HD + tid];
  if (tid < 8) used[tid] = 0;
  __syncthreads();
  float a = srowA[i];
  int sc = 0;
  for (int q = 0; q < 128; q++) sc += (ts[q] < a) ? 1 : 0;
  float4 r = rec[i];
  r.y = __int_as_float(sc);
  rec[i] = r;
  atomicOr(&used[sc>>5], 1u << (sc & 31));
  __syncthreads();
  if (tid < 8 && used[tid]) atomicOr(&segUsed[g*8 + tid], used[tid]);
}

// ---- edge pass 2 (decoder): rec slab staged in LDS ----
__global__ void __launch_bounds__(1024) k_edge2dec(
    const int* __restrict__ ei, const float4* __restrict__ rec,
    const int* __restrict__ nf2, float4* __restrict__ sums4,
    int2* __restrict__ missL, int* __restrict__ mcnt)
{
  __shared__ float sf[NNPG*4];     // 64 KB
  __shared__ float4 sRec[NNPG];    // 64 KB
  int g, j; swz(blockIdx.x, g, j);
  int tid = threadIdx.x;
  int gbase = g*NNPG;
  int nf = nf2[g];
  const int4* srcs4 = (const int4*)(ei + g*EPG + j*EPB);
  const int4* dsts4 = (const int4*)(ei + ET + g*EPG + j*EPB);
  int4 S = srcs4[tid], D = dsts4[tid];
  float4* sf4 = (float4*)sf;
  #pragma unroll
  for (int k = 0; k < 4; k++){
    sf4[4*tid + k] = make_float4(0.f,0.f,0.f,0.f);
    sRec[k*1024 + tid] = rec[gbase + k*1024 + tid];
  }
  __syncthreads();
  #define E2(s_, d_) { float4 r = sRec[(s_) - gbase]; int dl = (d_) - gbase; \
    int sb = __float_as_int(r.y); \
    atomicAdd(&sf[dl*4+0], r.z); atomicAdd(&sf[dl*4+1], r.x); \
    if (sb == nf) { atomicAdd(&sf[dl*4+2], r.z); atomicAdd(&sf[dl*4+3], r.x); } \
    else if (sb != 0) { int ix = atomicAdd(&mcnt[1], 1); \
      if (ix < MCAP) missL[ix] = make_int2(d_, s_); } }
  E2(S.x, D.x); E2(S.y, D.y); E2(S.z, D.z); E2(S.w, D.w);
  #undef E2
  __syncthreads();
  float4* sp = sums4 + (size_t)j*NTOT + gbase;
  #pragma unroll
  for (int k = 0; k < 4; k++) sp[4*tid + k] = sf4[4*tid + k];
}

// ---- decoder finish: acc -> relu -> out-proj -> tanh ----
__global__ void __launch_bounds__(256) k_dec_fin(
    const float4* __restrict__ rec, const float4* __restrict__ sums4,
    const float4* __restrict__ AC2, const float* __restrict__ b2,
    const float* __restrict__ ow, const float* __restrict__ ob,
    const int* __restrict__ nf2, const int2* __restrict__ missL,
    const int* __restrict__ mcnt, float* __restrict__ recon)
{
  __shared__ float4 sS[TN];
  __shared__ float4 sRA[TN];
  int bid = blockIdx.x, g = bid & 63, part = bid >> 6;
  int tid = threadIdx.x, lane = tid & 31, nrow = tid >> 5;
  int base = g*NNPG + part*TN;
  int nf = nf2[g];
  const float4* AC = AC2 + (size_t)g*NSEG*64;
  {
    int i = base + tid;
    sRA[tid] = rec[i];
    float4 a = sums4[0*NTOT + i], b = sums4[1*NTOT + i];
    float4 c = sums4[2*NTOT + i], d = sums4[3*NTOT + i];
    sS[tid] = make_float4(a.x+b.x+c.x+d.x, a.y+b.y+c.y+d.y,
                          a.z+b.z+c.z+d.z, a.w+b.w+c.w+d.w);
  }
  __syncthreads();
  const float4* q0 = AC + (size_t)lane*2;
  const float4* qn = AC + ((size_t)nf*32 + lane)*2;
  float4 A0 = q0[0], C0 = q0[1], An = qn[0], Cn = qn[1];
  float4 dA = make_float4(An.x-A0.x, An.y-A0.y, An.z-A0.z, An.w-A0.w);
  float4 dC = make_float4(Cn.x-C0.x, Cn.y-C0.y, Cn.z-C0.z, Cn.w-C0.w);
  float4 bb  = ((const float4*)b2)[lane];
  float4 owv = ((const float4*)ow)[lane];
  float obv = ob[0];
  int mc = mcnt[1]; mc = mc < MCAP ? mc : MCAP;
  for (int it = 0; it < TN/8; ++it){
    int li = it*8 + nrow;
    int i = base + li;
    float4 rA = sRA[li];
    float4 s4 = sS[li];
    float accx = fmaf(s4.x,A0.x, fmaf(s4.z,dA.x, fmaf(s4.y,C0.x, s4.w*dC.x)));
    float accy = fmaf(s4.x,A0.y, fmaf(s4.z,dA.y, fmaf(s4.y,C0.y, s4.w*dC.y)));
    float accz = fmaf(s4.x,A0.z, fmaf(s4.z,dA.z, fmaf(s4.y,C0.z, s4.w*dC.z)));
    float accw = fmaf(s4.x,A0.w, fmaf(s4.z,dA.w, fmaf(s4.y,C0.w, s4.w*dC.w)));
    if (mc > 0){
      for (int e = 0; e < mc; e++){
        int2 me = missL[e];
        if (me.x == i){
          float4 r = rec[me.y];
          int sb = __float_as_int(r.y);
          const float4* qm = AC + ((size_t)sb*32 + lane)*2;
          float4 qa = qm[0], qc = qm[1];
          accx = fmaf(r.z, qa.x-A0.x, fmaf(r.x, qc.x-C0.x, accx));
          accy = fmaf(r.z, qa.y-A0.y, fmaf(r.x, qc.y-C0.y, accy));
          accz = fmaf(r.z, qa.z-A0.z, fmaf(r.x, qc.z-C0.z, accz));
          accw = fmaf(r.z, qa.w-A0.w, fmaf(r.x, qc.w-C0.w, accw));
        }
      }
    }
    int si = __float_as_int(rA.y);
    bool m0 = (si == 0);
    float4 sa, sc;
    sa.x = m0 ? A0.x : An.x; sa.y = m0 ? A0.y : An.y; sa.z = m0 ? A0.z : An.z; sa.w = m0 ? A0.w : An.w;
    sc.x = m0 ? C0.x : Cn.x; sc.y = m0 ? C0.y : Cn.y; sc.z = m0 ? C0.z : Cn.z; sc.w = m0 ? C0.w : Cn.w;
    if (si != 0 && si != nf){
      const float4* qs = AC + ((size_t)si*32 + lane)*2;
      sa = qs[0]; sc = qs[1];
    }
    float d = rA.x, d2 = d*d, ca = rA.z*d;
    float hx = fmaxf(fmaf(d, accx, fmaf(ca, sa.x, d2*sc.x)) + bb.x, 0.f);
    float hy = fmaxf(fmaf(d, accy, fmaf(ca, sa.y, d2*sc.y)) + bb.y, 0.f);
    float hz = fmaxf(fmaf(d, accz, fmaf(ca, sa.z, d2*sc.z)) + bb.z, 0.f);
    float hw = fmaxf(fmaf(d, accw, fmaf(ca, sa.w, d2*sc.w)) + bb.w, 0.f);
    float dsum = hx*owv.x + hy*owv.y + hz*owv.z + hw*owv.w;
    for (int o2 = 16; o2 > 0; o2 >>= 1) dsum += __shfl_down(dsum, o2, 32);
    if (lane == 0) recon[i] = tanhf(dsum + obv);
  }
}

// ---------------- launch ----------------
extern "C" void kernel_launch(void* const* d_in, const int* in_sizes, int n_in,
                              void* d_out, int out_size, void* d_ws, size_t ws_size,
                              hipStream_t stream){
  (void)in_sizes; (void)n_in; (void)out_size; (void)ws_size;
  const float* x      = (const float*)d_in[0];
  const float* eps    = (const float*)d_in[1];
  const float* enc_w1 = (const float*)d_in[2];
  const float* enc_b1 = (const float*)d_in[3];
  const float* enc_w2 = (const float*)d_in[4];
  const float* enc_b2 = (const float*)d_in[5];
  const float* mu_w   = (const float*)d_in[6];
  const float* mu_b   = (const float*)d_in[7];
  const float* lv_w   = (const float*)d_in[8];
  const float* lv_b   = (const float*)d_in[9];
  const float* zn_w   = (const float*)d_in[10];
  const float* zn_b   = (const float*)d_in[11];
  const float* dec_w1 = (const float*)d_in[12];
  const float* dec_b1 = (const float*)d_in[13];
  const float* dec_w2 = (const float*)d_in[14];
  const float* dec_b2 = (const float*)d_in[15];
  const float* out_w  = (const float*)d_in[16];
  const float* out_b  = (const float*)d_in[17];
  const int*   ei     = (const int*)d_in[18];

  float* out       = (float*)d_out;
  float* out_recon = out;
  float* out_mu    = out + NTOT;
  float* out_lv    = out_mu + BG*LD;
  float* out_z     = out_lv + BG*LD;

  char* w = (char*)d_ws;
  size_t off_b = 0;
  auto alloc = [&](size_t bytes)->void*{
    void* p = w + off_b;
    off_b += (bytes + 255) & ~(size_t)255;
    return p;
  };
  // region A (16MB): cntJ[0:4M) + accJ[4M:12M) early; sums4[0:16M) later
  char*   regA   = (char*) alloc((size_t)4*NTOT*16);
  int*    cntJ   = (int*)   regA;
  float2* accJ   = (float2*)(regA + (size_t)4*NTOT*4);
  float4* sums4  = (float4*)regA;
  float2* xd     = (float2*)alloc((size_t)NTOT*8);
  float4* rec    = (float4*)alloc((size_t)NTOT*16);
  float*  srowA  = (float*) alloc((size_t)NTOT*4);
  int2*   missL  = (int2*)  alloc((size_t)MCAP*8);
  float*  t1     = (float*) alloc(128*4);
  int*    nf1    = (int*)   alloc(256);
  int*    nf2    = (int*)   alloc(BG*4);
  int*    segU1  = (int*)   alloc(8*4);
  int*    segU   = (int*)   alloc(BG*8*4);
  float*  t2     = (float*) alloc((size_t)BG*HD*4);
  float*  ushG   = (float*) alloc((size_t)BG*HD*4);
  float*  AC1    = (float*) alloc((size_t)NSEG*256*4);
  float*  AC2    = (float*) alloc((size_t)BG*NSEG*256*4);
  float*  hgsum  = (float*) alloc((size_t)BG*HD*4);
  int*    mcnt   = (int*)   alloc(256);

  // 11 dispatches; zeroing folded into k_count's rider block

  k_count <<<257, 1024, 0, stream>>>(ei, enc_w1, enc_b1, cntJ, t1, nf1,
                                     hgsum, mcnt, segU1, segU);
  k_edge1 <<<256, 1024, 0, stream>>>(ei, cntJ, x, xd, accJ);
  k_pack  <<<NTOT/256, 256, 0, stream>>>(xd, accJ, t1, rec, srowA, segU1);
  // encoder table rows {0, nf, used}
  k_tabrows<<<1, 1024, 0, stream>>>(enc_w1, enc_b1, enc_w2, segU1, nf1, AC1);

  k_edge2enc<<<256, 1024, 0, stream>>>(ei, rec, nf1, sums4, missL, mcnt);
  k_enc_fin <<<1024, 256, 0, stream>>>(rec, sums4, (const float4*)AC1, enc_b2,
                                       nf1, missL, mcnt, hgsum);

  k_small<<<BG, 128, 0, stream>>>(hgsum, mu_w, mu_b, lv_w, lv_b, eps,
                                  zn_w, zn_b, dec_w1, dec_b1,
                                  out_mu, out_lv, out_z, t2, ushG, nf2);

  k_seg2<<<NTOT/256, 256, 0, stream>>>(t2, srowA, rec, segU);

  // decoder table rows {0, nf, used} per graph
  k_tabrows<<<BG, 1024, 0, stream>>>(ushG, dec_b1, dec_w2, segU, nf2, AC2);

  k_edge2dec<<<256, 1024, 0, stream>>>(ei, rec, nf2, sums4, missL, mcnt);
  k_dec_fin <<<1024, 256, 0, stream>>>(rec, sums4, (const float4*)AC2, dec_b2,
                                       out_w, out_b, nf2, missL, mcnt, out_recon);
}

// Round 20
// 149.907 us; speedup vs baseline: 1.2121x; 1.1133x over previous
//
#include <hip/hip_runtime.h>
#include <math.h>

#define NTOT 262144   // total nodes
#define BG   64       // graphs
#define NNPG 4096     // nodes per graph
#define ET   1048576  // directed edges
#define EPG  16384    // edges per graph
#define EPB  4096     // edges per sub-block (4 sub-blocks/graph)
#define HD   128
#define LD   64
#define NSEG 129
#define TN   256
#define MCAP ET       // miss-list capacity (int2 entries)

// XCD-bijective swizzle: all 4 sub-blocks of graph g share (b&7) -> one XCD L2
__device__ __forceinline__ void swz(int b, int& g, int& j){
  int xcd = b & 7, q = b >> 3;
  g = (q >> 2)*8 + xcd;
  j = q & 3;
}

// ---- base table rows {0, nf} (no segU dependency); 1024 thr = 8 qg x 128 k --
__device__ __forceinline__ void tab_base(
    int tid, const float* __restrict__ wsrc, const float* __restrict__ bsrc,
    const float* __restrict__ w2, float* __restrict__ tout, int* __restrict__ nfout,
    float* __restrict__ ACg,
    float* ws, float* bs, int* ks, float (*red)[128][4], int* nfsh)
{
  int k = tid & 127, qg = tid >> 7;
  if (qg == 0){
    float w = wsrc[k], b = bsrc[k];
    float t; int kind;
    if (w != 0.0f){ t = -b / w; kind = (w > 0.0f) ? 0 : 1; }
    else          { t = INFINITY; kind = 2; }
    ws[k] = w; bs[k] = b; ks[k] = kind;
    if (tout) tout[k] = t;
  }
  __syncthreads();
  if (tid == 0){
    int c = 0;
    for (int q = 0; q < 128; q++) c += (ks[q] != 2) ? 1 : 0;
    *nfsh = c;
    if (nfout) *nfout = c;
  }
  float a0=0.f, c0=0.f, an=0.f, cn=0.f;
  #pragma unroll
  for (int u = 0; u < 16; u++){
    int q = qg*16 + u;
    float v = w2[q*HD + k];
    int kd = ks[q];
    float wq = ws[q], bq = bs[q];
    bool m0 = (kd == 1) || (kd == 2 && bq > 0.f);
    bool mn = (kd == 0) || (kd == 2 && bq > 0.f);
    float wv = wq*v, bv = bq*v;
    a0 += m0 ? wv : 0.f; c0 += m0 ? bv : 0.f;
    an += mn ? wv : 0.f; cn += mn ? bv : 0.f;
  }
  red[qg][k][0]=a0; red[qg][k][1]=c0; red[qg][k][2]=an; red[qg][k][3]=cn;
  __syncthreads();
  int nf = *nfsh;
  int base = (k>>2)*8 + (k&3);
  if (qg == 0){
    float A0=0.f,C0=0.f,An=0.f,Cn=0.f;
    #pragma unroll
    for (int p = 0; p < 8; p++){
      A0+=red[p][k][0]; C0+=red[p][k][1]; An+=red[p][k][2]; Cn+=red[p][k][3];
    }
    ACg[base] = A0; ACg[base+4] = C0;
    ACg[(size_t)nf*256 + base] = An; ACg[(size_t)nf*256 + base + 4] = Cn;
  }
}

// ---- extras-only table rows (rare; early-out when bitmap == {0,nf}) ----
__device__ __forceinline__ void tab_extras(
    int g, int tid, const float* __restrict__ wsrc, const float* __restrict__ bsrc,
    const float* __restrict__ w2, const int* __restrict__ segUsed,
    const int* __restrict__ nfA, float* __restrict__ ACbase,
    float* ws, float* bs, float* tsh, int* ks, int* rr, float (*red)[128][4])
{
  int nf = nfA[g];
  unsigned any = 0;
  for (int wd = 0; wd < 5; wd++){
    unsigned m = (unsigned)segUsed[g*8 + wd];
    if (wd == 0) m &= ~1u;
    if ((nf >> 5) == wd) m &= ~(1u << (nf & 31));
    any |= m;
  }
  if (any == 0) return;          // uniform early-out (the practical case)
  int k = tid & 127, qg = tid >> 7;
  if (qg == 0){
    float w = wsrc[g*HD + k], b = bsrc[k];
    float t; int kind;
    if (w != 0.0f){ t = -b / w; kind = (w > 0.0f) ? 0 : 1; }
    else          { t = INFINITY; kind = 2; }
    ws[k] = w; bs[k] = b; tsh[k] = t; ks[k] = kind;
  }
  __syncthreads();
  if (qg == 0){
    float t = tsh[k];
    int r = 0;
    for (int q = 0; q < 128; q++){
      if (ks[q] != 2){
        float tq = tsh[q];
        if (tq < t || (tq == t && q < k)) r++;
      }
    }
    rr[k] = r;
  }
  __syncthreads();
  float* ACg = ACbase + (size_t)g*NSEG*256;
  int base = (k>>2)*8 + (k&3);
  for (int wd = 0; wd < 5; wd++){
    unsigned m = (unsigned)segUsed[g*8 + wd];
    if (wd == 0) m &= ~1u;
    if ((nf >> 5) == wd) m &= ~(1u << (nf & 31));
    while (m){
      int bit = __ffs(m) - 1;
      m &= m - 1;
      int s = wd*32 + bit;
      float pa=0.f, pc=0.f;
      #pragma unroll
      for (int u = 0; u < 16; u++){
        int q = qg*16 + u;
        int kd = ks[q];
        bool act = (kd == 0) ? (rr[q] < s) : (kd == 1) ? (rr[q] >= s) : (bs[q] > 0.f);
        float v = act ? w2[q*HD + k] : 0.f;
        pa = fmaf(ws[q], v, pa); pc = fmaf(bs[q], v, pc);
      }
      red[qg][k][0]=pa; red[qg][k][1]=pc;
      __syncthreads();
      if (qg == 0){
        float A=0.f,C=0.f;
        #pragma unroll
        for (int p = 0; p < 8; p++){ A+=red[p][k][0]; C+=red[p][k][1]; }
        ACg[(size_t)s*256 + base] = A; ACg[(size_t)s*256 + base + 4] = C;
      }
      __syncthreads();
    }
  }
}

// ---- count: LDS histogram per sub-block -> planar cntJ; block 256 = rider:
//      zero hgsum/mcnt/segU1/segU + t1/nf1 + AC1 rows {0,nf} ----
__global__ void __launch_bounds__(1024) k_count(const int* __restrict__ ei,
                                                const float* __restrict__ w1,
                                                const float* __restrict__ b1,
                                                const float* __restrict__ w2,
                                                int* __restrict__ cntJ,
                                                float* __restrict__ t1, int* __restrict__ nfp,
                                                float* __restrict__ AC1,
                                                float* __restrict__ hgsum,
                                                int* __restrict__ mcnt,
                                                int* __restrict__ segU1,
                                                int* __restrict__ segU){
  __shared__ union {
    int h[NNPG];
    struct { float ws[128], bs[128]; int ks[128], nfsh;
             float red[8][128][4]; } t;
  } u;
  int tid = threadIdx.x;
  if (blockIdx.x == 256){
    for (int idx = tid; idx < BG*HD; idx += 1024) hgsum[idx] = 0.f;
    if (tid < 2) mcnt[tid] = 0;
    if (tid < 8) segU1[tid] = 0;
    if (tid < BG*8) segU[tid] = 0;
    tab_base(tid, w1, b1, w2, t1, nfp, AC1,
             u.t.ws, u.t.bs, u.t.ks, u.t.red, &u.t.nfsh);
    return;
  }
  int g, j; swz(blockIdx.x, g, j);
  #pragma unroll
  for (int k = tid; k < NNPG; k += 1024) u.h[k] = 0;
  __syncthreads();
  int gbase = g*NNPG;
  const int4* dsts4 = (const int4*)(ei + ET + g*EPG + j*EPB);
  int4 D = dsts4[tid];
  atomicAdd(&u.h[D.x - gbase], 1); atomicAdd(&u.h[D.y - gbase], 1);
  atomicAdd(&u.h[D.z - gbase], 1); atomicAdd(&u.h[D.w - gbase], 1);
  __syncthreads();
  int* plane = cntJ + j*NTOT + gbase;
  #pragma unroll
  for (int k = tid; k < NNPG; k += 1024) plane[k] = u.h[k];
}

// ---- edge pass 1 (fused dinv/xd): per-dest sums of (d_s*x_s, d_s) ----
__global__ void __launch_bounds__(1024) k_edge1(
    const int* __restrict__ ei, const int* __restrict__ cntJ,
    const float* __restrict__ x, float2* __restrict__ xd,
    float2* __restrict__ accJ)
{
  __shared__ float2 sxd[NNPG];    // 32 KB
  __shared__ float ax[NNPG];      // 16 KB
  __shared__ float s1[NNPG];      // 16 KB
  int tid = threadIdx.x;
  int g, j; swz(blockIdx.x, g, j);
  int gbase = g*NNPG;
  const int4* srcs4 = (const int4*)(ei + g*EPG + j*EPB);
  const int4* dsts4 = (const int4*)(ei + ET + g*EPG + j*EPB);
  int4 S = srcs4[tid], D = dsts4[tid];
  {
    int i0 = 4*tid;
    int4 c0 = *(const int4*)(cntJ + 0*NTOT + gbase + i0);
    int4 c1 = *(const int4*)(cntJ + 1*NTOT + gbase + i0);
    int4 c2 = *(const int4*)(cntJ + 2*NTOT + gbase + i0);
    int4 c3 = *(const int4*)(cntJ + 3*NTOT + gbase + i0);
    float4 xv = *(const float4*)(x + gbase + i0);
    float2 p0 = make_float2(xv.x, rsqrtf((float)(c0.x+c1.x+c2.x+c3.x) + 1.0f));
    float2 p1 = make_float2(xv.y, rsqrtf((float)(c0.y+c1.y+c2.y+c3.y) + 1.0f));
    float2 p2 = make_float2(xv.z, rsqrtf((float)(c0.z+c1.z+c2.z+c3.z) + 1.0f));
    float2 p3 = make_float2(xv.w, rsqrtf((float)(c0.w+c1.w+c2.w+c3.w) + 1.0f));
    sxd[i0+0] = p0; sxd[i0+1] = p1; sxd[i0+2] = p2; sxd[i0+3] = p3;
    if (j == 0){
      float4* xd4 = (float4*)(xd + gbase);
      xd4[2*tid+0] = make_float4(p0.x, p0.y, p1.x, p1.y);
      xd4[2*tid+1] = make_float4(p2.x, p2.y, p3.x, p3.y);
    }
    *(float4*)(ax + i0) = make_float4(0.f,0.f,0.f,0.f);
    *(float4*)(s1 + i0) = make_float4(0.f,0.f,0.f,0.f);
  }
  __syncthreads();
  #define P1(s_, d_) { float2 sd = sxd[(s_) - gbase]; int dl = (d_) - gbase; \
    atomicAdd(&ax[dl], sd.y * sd.x); \
    atomicAdd(&s1[dl], sd.y); }
  P1(S.x, D.x); P1(S.y, D.y); P1(S.z, D.z); P1(S.w, D.w);
  #undef P1
  __syncthreads();
  float4* ap = (float4*)(accJ + (size_t)j*NTOT + gbase);
  ap[2*tid+0] = make_float4(ax[4*tid+0], s1[4*tid+0], ax[4*tid+1], s1[4*tid+1]);
  ap[2*tid+1] = make_float4(ax[4*tid+2], s1[4*tid+2], ax[4*tid+3], s1[4*tid+3]);
}

// ---- pack per-node record: rec[i] = (d, d*ax, d*srow, segE) + segE bitmap ----
__global__ void k_pack(const float2* __restrict__ xd, const float2* __restrict__ accJ,
                       const float* __restrict__ t1,
                       float4* __restrict__ rec, float* __restrict__ srowA,
                       int* __restrict__ segU1){
  __shared__ float ts[128];
  __shared__ int used[8];
  int tid = threadIdx.x;
  if (tid < 128) ts[tid] = t1[tid];
  if (tid < 8) used[tid] = 0;
  __syncthreads();
  int i = blockIdx.x*256 + tid;
  float2 xdv = xd[i];
  float2 a0 = accJ[0*NTOT + i], a1 = accJ[1*NTOT + i];
  float2 a2 = accJ[2*NTOT + i], a3 = accJ[3*NTOT + i];
  float axs = (a0.x + a1.x) + (a2.x + a3.x);
  float s1s = (a0.y + a1.y) + (a2.y + a3.y);
  float di = xdv.y;
  float ax = di * (di * xdv.x + axs);
  float sr = di * (di + s1s);
  int sc = 0;
  for (int q = 0; q < 128; q++) sc += (ts[q] < ax) ? 1 : 0;
  rec[i] = make_float4(di, di*ax, di*sr, __int_as_float(sc));
  srowA[i] = sr;
  atomicOr(&used[sc>>5], 1u << (sc & 31));
  __syncthreads();
  if (tid < 8 && used[tid]) atomicOr(&segU1[tid], used[tid]);
}

// ---- edge pass 2 (encoder): direct rec reads, 64KB sf; block 256 = extras ----
__global__ void __launch_bounds__(1024) k_edge2enc(
    const int* __restrict__ ei, const float4* __restrict__ rec,
    const int* __restrict__ nfp, float4* __restrict__ sums4,
    int2* __restrict__ missL, int* __restrict__ mcnt,
    const float* __restrict__ enc_w1, const float* __restrict__ enc_b1,
    const float* __restrict__ enc_w2, const int* __restrict__ segU1,
    float* __restrict__ AC1)
{
  __shared__ union {
    float sf[NNPG*4];                                   // 64 KB
    struct { float ws[128], bs[128], tsh[128];
             int ks[128], rr[128]; float red[8][128][4]; } t;
  } u;
  int tid = threadIdx.x;
  if (blockIdx.x == 256){
    tab_extras(0, tid, enc_w1, enc_b1, enc_w2, segU1, nfp, AC1,
               u.t.ws, u.t.bs, u.t.tsh, u.t.ks, u.t.rr, u.t.red);
    return;
  }
  int g, j; swz(blockIdx.x, g, j);
  int gbase = g*NNPG;
  int nf = nfp[0];
  const int4* srcs4 = (const int4*)(ei + g*EPG + j*EPB);
  const int4* dsts4 = (const int4*)(ei + ET + g*EPG + j*EPB);
  int4 S = srcs4[tid], D = dsts4[tid];
  float4 r1 = rec[S.x], r2 = rec[S.y], r3 = rec[S.z], r4 = rec[S.w];
  float4* sf4 = (float4*)u.sf;
  #pragma unroll
  for (int k = 0; k < 4; k++) sf4[tid + k*1024] = make_float4(0.f,0.f,0.f,0.f);
  __syncthreads();
  #define E1(r_, s_, d_) { int dl = (d_) - gbase; int sb = __float_as_int(r_.w); \
    atomicAdd(&u.sf[dl*4+0], r_.y); atomicAdd(&u.sf[dl*4+1], r_.x); \
    if (sb == nf) { atomicAdd(&u.sf[dl*4+2], r_.y); atomicAdd(&u.sf[dl*4+3], r_.x); } \
    else if (sb != 0) { int ix = atomicAdd(&mcnt[0], 1); \
      if (ix < MCAP) missL[ix] = make_int2(d_, s_); } }
  E1(r1, S.x, D.x); E1(r2, S.y, D.y); E1(r3, S.z, D.z); E1(r4, S.w, D.w);
  #undef E1
  __syncthreads();
  float4* sp = sums4 + (size_t)j*NTOT + gbase;
  #pragma unroll
  for (int k = 0; k < 4; k++) sp[tid + k*1024] = sf4[tid + k*1024];
}

// ---- encoder finish: acc -> relu -> mean-pool ----
__global__ void __launch_bounds__(256) k_enc_fin(
    const float4* __restrict__ rec, const float4* __restrict__ sums4,
    const float4* __restrict__ AC, const float* __restrict__ b2,
    const int* __restrict__ nfp, const int2* __restrict__ missL,
    const int* __restrict__ mcnt, float* __restrict__ hgsum)
{
  __shared__ float4 sS[TN];
  __shared__ float4 sRA[TN];
  __shared__ float red[256*4];
  int bid = blockIdx.x, g = bid & 63, part = bid >> 6;   // 1024 blocks
  int tid = threadIdx.x, lane = tid & 31, nrow = tid >> 5;
  int base = g*NNPG + part*TN;
  int nf = nfp[0];
  {
    int i = base + tid;
    sRA[tid] = rec[i];
    float4 a = sums4[0*NTOT + i], b = sums4[1*NTOT + i];
    float4 c = sums4[2*NTOT + i], d = sums4[3*NTOT + i];
    sS[tid] = make_float4(a.x+b.x+c.x+d.x, a.y+b.y+c.y+d.y,
                          a.z+b.z+c.z+d.z, a.w+b.w+c.w+d.w);
  }
  __syncthreads();
  const float4* q0 = AC + (size_t)lane*2;
  const float4* qn = AC + ((size_t)nf*32 + lane)*2;
  float4 A0 = q0[0], C0 = q0[1], An = qn[0], Cn = qn[1];
  float4 dA = make_float4(An.x-A0.x, An.y-A0.y, An.z-A0.z, An.w-A0.w);
  float4 dC = make_float4(Cn.x-C0.x, Cn.y-C0.y, Cn.z-C0.z, Cn.w-C0.w);
  float4 bb = ((const float4*)b2)[lane];
  int mc = mcnt[0]; mc = mc < MCAP ? mc : MCAP;
  float gx=0.f, gy=0.f, gz=0.f, gw=0.f;
  for (int it = 0; it < TN/8; ++it){
    int li = it*8 + nrow;
    int i = base + li;
    float4 rA = sRA[li];
    float4 s4 = sS[li];
    float accx = fmaf(s4.x,A0.x, fmaf(s4.z,dA.x, fmaf(s4.y,C0.x, s4.w*dC.x)));
    float accy = fmaf(s4.x,A0.y, fmaf(s4.z,dA.y, fmaf(s4.y,C0.y, s4.w*dC.y)));
    float accz = fmaf(s4.x,A0.z, fmaf(s4.z,dA.z, fmaf(s4.y,C0.z, s4.w*dC.z)));
    float accw = fmaf(s4.x,A0.w, fmaf(s4.z,dA.w, fmaf(s4.y,C0.w, s4.w*dC.w)));
    if (mc > 0){          // rare correctness path (off-{0,nf} source segments)
      for (int e = 0; e < mc; e++){
        int2 me = missL[e];
        if (me.x == i){
          float4 r = rec[me.y];
          int sb = __float_as_int(r.w);
          const float4* qm = AC + ((size_t)sb*32 + lane)*2;
          float4 qa = qm[0], qc = qm[1];
          accx = fmaf(r.y, qa.x-A0.x, fmaf(r.x, qc.x-C0.x, accx));
          accy = fmaf(r.y, qa.y-A0.y, fmaf(r.x, qc.y-C0.y, accy));
          accz = fmaf(r.y, qa.z-A0.z, fmaf(r.x, qc.z-C0.z, accz));
          accw = fmaf(r.y, qa.w-A0.w, fmaf(r.x, qc.w-C0.w, accw));
        }
      }
    }
    int si = __float_as_int(rA.w);
    bool m0 = (si == 0);
    float4 sa, sc;
    sa.x = m0 ? A0.x : An.x; sa.y = m0 ? A0.y : An.y; sa.z = m0 ? A0.z : An.z; sa.w = m0 ? A0.w : An.w;
    sc.x = m0 ? C0.x : Cn.x; sc.y = m0 ? C0.y : Cn.y; sc.z = m0 ? C0.z : Cn.z; sc.w = m0 ? C0.w : Cn.w;
    if (si != 0 && si != nf){
      const float4* qs = AC + ((size_t)si*32 + lane)*2;
      sa = qs[0]; sc = qs[1];
    }
    float d = rA.x, d2 = d*d, ca = rA.y*d;
    gx += fmaxf(fmaf(d, accx, fmaf(ca, sa.x, d2*sc.x)) + bb.x, 0.f);
    gy += fmaxf(fmaf(d, accy, fmaf(ca, sa.y, d2*sc.y)) + bb.y, 0.f);
    gz += fmaxf(fmaf(d, accz, fmaf(ca, sa.z, d2*sc.z)) + bb.z, 0.f);
    gw += fmaxf(fmaf(d, accw, fmaf(ca, sa.w, d2*sc.w)) + bb.w, 0.f);
  }
  __syncthreads();
  red[tid*4+0] = gx; red[tid*4+1] = gy; red[tid*4+2] = gz; red[tid*4+3] = gw;
  __syncthreads();
  if (nrow == 0){
    float tx=0.f, ty=0.f, tz=0.f, tw=0.f;
    for (int r2 = 0; r2 < 8; r2++){
      int t2 = (r2*32 + lane)*4;
      tx += red[t2]; ty += red[t2+1]; tz += red[t2+2]; tw += red[t2+3];
    }
    atomicAdd(&hgsum[g*HD + lane*4 + 0], tx);
    atomicAdd(&hgsum[g*HD + lane*4 + 1], ty);
    atomicAdd(&hgsum[g*HD + lane*4 + 2], tz);
    atomicAdd(&hgsum[g*HD + lane*4 + 3], tw);
  }
}

// ------- per-graph dense chain + AC2 rows {0,nf} (64 blocks x 1024 thr) -----
__global__ void __launch_bounds__(1024) k_small(
    const float* __restrict__ hgsum,
    const float* __restrict__ mu_w, const float* __restrict__ mu_b,
    const float* __restrict__ lv_w, const float* __restrict__ lv_b,
    const float* __restrict__ eps,
    const float* __restrict__ zn_w, const float* __restrict__ zn_b,
    const float* __restrict__ dec_w1, const float* __restrict__ dec_b1,
    const float* __restrict__ dec_w2,
    float* __restrict__ out_mu, float* __restrict__ out_lv, float* __restrict__ out_z,
    float* __restrict__ t2, float* __restrict__ ushG, int* __restrict__ nf2,
    float* __restrict__ AC2)
{
  __shared__ float hg[128], zsh[64], znsh[128], ush[128], bsx[128];
  __shared__ int ks[128], nfsh;
  __shared__ float red[8][128][4];
  int g = blockIdx.x, tid = threadIdx.x;
  if (tid < 128) hg[tid] = hgsum[g*HD + tid] * (1.0f/4096.0f);
  __syncthreads();
  if (tid < 64){
    int l = tid;
    float m = mu_b[l], v = lv_b[l];
    for (int k = 0; k < HD; k++){
      float hv = hg[k];
      m = fmaf(hv, mu_w[k*LD + l], m);
      v = fmaf(hv, lv_w[k*LD + l], v);
    }
    int o = g*LD + l;
    out_mu[o] = m; out_lv[o] = v;
    float zv = fmaf(expf(0.5f*v), eps[o], m);
    out_z[o] = zv; zsh[l] = zv;
  }
  __syncthreads();
  if (tid < 128){
    float acc = zn_b[tid];
    for (int l = 0; l < LD; l++) acc = fmaf(zsh[l], zn_w[l*HD + tid], acc);
    znsh[tid] = acc;
  }
  __syncthreads();
  if (tid < 128){
    float acc = 0.f;
    for (int j = 0; j < HD; j++) acc = fmaf(znsh[j], dec_w1[j*HD + tid], acc);
    ushG[g*HD + tid] = acc;
    ush[tid] = acc;
    float b = dec_b1[tid];
    bsx[tid] = b;
    float t; int kind;
    if (acc != 0.0f){ t = -b / acc; kind = (acc > 0.0f) ? 0 : 1; }
    else            { t = INFINITY; kind = 2; }
    t2[g*HD + tid] = t; ks[tid] = kind;
  }
  __syncthreads();
  if (tid == 0){
    int c = 0;
    for (int q = 0; q < 128; q++) c += (ks[q] != 2) ? 1 : 0;
    nf2[g] = c; nfsh = c;
  }
  __syncthreads();
  // AC2 rows {0, nf} via q-split
  int k = tid & 127, qg = tid >> 7;
  float a0=0.f, c0=0.f, an=0.f, cn=0.f;
  #pragma unroll
  for (int u = 0; u < 16; u++){
    int q = qg*16 + u;
    float v = dec_w2[q*HD + k];
    int kd = ks[q];
    float wq = ush[q], bq = bsx[q];
    bool m0 = (kd == 1) || (kd == 2 && bq > 0.f);
    bool mn = (kd == 0) || (kd == 2 && bq > 0.f);
    float wv = wq*v, bv = bq*v;
    a0 += m0 ? wv : 0.f; c0 += m0 ? bv : 0.f;
    an += mn ? wv : 0.f; cn += mn ? bv : 0.f;
  }
  red[qg][k][0]=a0; red[qg][k][1]=c0; red[qg][k][2]=an; red[qg][k][3]=cn;
  __syncthreads();
  if (qg == 0){
    float A0=0.f,C0=0.f,An=0.f,Cn=0.f;
    #pragma unroll
    for (int p = 0; p < 8; p++){
      A0+=red[p][k][0]; C0+=red[p][k][1]; An+=red[p][k][2]; Cn+=red[p][k][3];
    }
    float* ACg = AC2 + (size_t)g*NSEG*256;
    int base = (k>>2)*8 + (k&3);
    int nf = nfsh;
    ACg[base] = A0; ACg[base+4] = C0;
    ACg[(size_t)nf*256 + base] = An; ACg[(size_t)nf*256 + base + 4] = Cn;
  }
}

// segD per node -> rec.y (coalesced float4 RMW) + used bitmap
__global__ void k_seg2(const float* __restrict__ t2, const float* __restrict__ srowA,
                       float4* __restrict__ rec, int* __restrict__ segUsed){
  __shared__ float ts[128];
  __shared__ int used[8];
  int tid = threadIdx.x;
  int i = blockIdx.x*256 + tid;
  int g = blockIdx.x >> 4;
  if (tid < 128) ts[tid] = t2[g*HD + tid];
  if (tid < 8) used[tid] = 0;
  __syncthreads();
  float a = srowA[i];
  int sc = 0;
  for (int q = 0; q < 128; q++) sc += (ts[q] < a) ? 1 : 0;
  float4 r = rec[i];
  r.y = __int_as_float(sc);
  rec[i] = r;
  atomicOr(&used[sc>>5], 1u << (sc & 31));
  __syncthreads();
  if (tid < 8 && used[tid]) atomicOr(&segUsed[g*8 + tid], used[tid]);
}

// ---- edge pass 2 (decoder): direct rec reads; blocks 256..319 = extras ----
__global__ void __launch_bounds__(1024) k_edge2dec(
    const int* __restrict__ ei, const float4* __restrict__ rec,
    const int* __restrict__ nf2, float4* __restrict__ sums4,
    int2* __restrict__ missL, int* __restrict__ mcnt,
    const float* __restrict__ ushG, const float* __restrict__ dec_b1,
    const float* __restrict__ dec_w2, const int* __restrict__ segU,
    float* __restrict__ AC2)
{
  __shared__ union {
    float sf[NNPG*4];                                   // 64 KB
    struct { float ws[128], bs[128], tsh[128];
             int ks[128], rr[128]; float red[8][128][4]; } t;
  } u;
  int tid = threadIdx.x;
  if (blockIdx.x >= 256){
    tab_extras(blockIdx.x - 256, tid, ushG, dec_b1, dec_w2, segU, nf2, AC2,
               u.t.ws, u.t.bs, u.t.tsh, u.t.ks, u.t.rr, u.t.red);
    return;
  }
  int g, j; swz(blockIdx.x, g, j);
  int gbase = g*NNPG;
  int nf = nf2[g];
  const int4* srcs4 = (const int4*)(ei + g*EPG + j*EPB);
  const int4* dsts4 = (const int4*)(ei + ET + g*EPG + j*EPB);
  int4 S = srcs4[tid], D = dsts4[tid];
  float4 r1 = rec[S.x], r2 = rec[S.y], r3 = rec[S.z], r4 = rec[S.w];
  float4* sf4 = (float4*)u.sf;
  #pragma unroll
  for (int k = 0; k < 4; k++) sf4[tid + k*1024] = make_float4(0.f,0.f,0.f,0.f);
  __syncthreads();
  #define E2(r_, s_, d_) { int dl = (d_) - gbase; int sb = __float_as_int(r_.y); \
    atomicAdd(&u.sf[dl*4+0], r_.z); atomicAdd(&u.sf[dl*4+1], r_.x); \
    if (sb == nf) { atomicAdd(&u.sf[dl*4+2], r_.z); atomicAdd(&u.sf[dl*4+3], r_.x); } \
    else if (sb != 0) { int ix = atomicAdd(&mcnt[1], 1); \
      if (ix < MCAP) missL[ix] = make_int2(d_, s_); } }
  E2(r1, S.x, D.x); E2(r2, S.y, D.y); E2(r3, S.z, D.z); E2(r4, S.w, D.w);
  #undef E2
  __syncthreads();
  float4* sp = sums4 + (size_t)j*NTOT + gbase;
  #pragma unroll
  for (int k = 0; k < 4; k++) sp[tid + k*1024] = sf4[tid + k*1024];
}

// ---- decoder finish: acc -> relu -> out-proj -> tanh ----
__global__ void __launch_bounds__(256) k_dec_fin(
    const float4* __restrict__ rec, const float4* __restrict__ sums4,
    const float4* __restrict__ AC2, const float* __restrict__ b2,
    const float* __restrict__ ow, const float* __restrict__ ob,
    const int* __restrict__ nf2, const int2* __restrict__ missL,
    const int* __restrict__ mcnt, float* __restrict__ recon)
{
  __shared__ float4 sS[TN];
  __shared__ float4 sRA[TN];
  int bid = blockIdx.x, g = bid & 63, part = bid >> 6;
  int tid = threadIdx.x, lane = tid & 31, nrow = tid >> 5;
  int base = g*NNPG + part*TN;
  int nf = nf2[g];
  const float4* AC = AC2 + (size_t)g*NSEG*64;
  {
    int i = base + tid;
    sRA[tid] = rec[i];
    float4 a = sums4[0*NTOT + i], b = sums4[1*NTOT + i];
    float4 c = sums4[2*NTOT + i], d = sums4[3*NTOT + i];
    sS[tid] = make_float4(a.x+b.x+c.x+d.x, a.y+b.y+c.y+d.y,
                          a.z+b.z+c.z+d.z, a.w+b.w+c.w+d.w);
  }
  __syncthreads();
  const float4* q0 = AC + (size_t)lane*2;
  const float4* qn = AC + ((size_t)nf*32 + lane)*2;
  float4 A0 = q0[0], C0 = q0[1], An = qn[0], Cn = qn[1];
  float4 dA = make_float4(An.x-A0.x, An.y-A0.y, An.z-A0.z, An.w-A0.w);
  float4 dC = make_float4(Cn.x-C0.x, Cn.y-C0.y, Cn.z-C0.z, Cn.w-C0.w);
  float4 bb  = ((const float4*)b2)[lane];
  float4 owv = ((const float4*)ow)[lane];
  float obv = ob[0];
  int mc = mcnt[1]; mc = mc < MCAP ? mc : MCAP;
  for (int it = 0; it < TN/8; ++it){
    int li = it*8 + nrow;
    int i = base + li;
    float4 rA = sRA[li];
    float4 s4 = sS[li];
    float accx = fmaf(s4.x,A0.x, fmaf(s4.z,dA.x, fmaf(s4.y,C0.x, s4.w*dC.x)));
    float accy = fmaf(s4.x,A0.y, fmaf(s4.z,dA.y, fmaf(s4.y,C0.y, s4.w*dC.y)));
    float accz = fmaf(s4.x,A0.z, fmaf(s4.z,dA.z, fmaf(s4.y,C0.z, s4.w*dC.z)));
    float accw = fmaf(s4.x,A0.w, fmaf(s4.z,dA.w, fmaf(s4.y,C0.w, s4.w*dC.w)));
    if (mc > 0){
      for (int e = 0; e < mc; e++){
        int2 me = missL[e];
        if (me.x == i){
          float4 r = rec[me.y];
          int sb = __float_as_int(r.y);
          const float4* qm = AC + ((size_t)sb*32 + lane)*2;
          float4 qa = qm[0], qc = qm[1];
          accx = fmaf(r.z, qa.x-A0.x, fmaf(r.x, qc.x-C0.x, accx));
          accy = fmaf(r.z, qa.y-A0.y, fmaf(r.x, qc.y-C0.y, accy));
          accz = fmaf(r.z, qa.z-A0.z, fmaf(r.x, qc.z-C0.z, accz));
          accw = fmaf(r.z, qa.w-A0.w, fmaf(r.x, qc.w-C0.w, accw));
        }
      }
    }
    int si = __float_as_int(rA.y);
    bool m0 = (si == 0);
    float4 sa, sc;
    sa.x = m0 ? A0.x : An.x; sa.y = m0 ? A0.y : An.y; sa.z = m0 ? A0.z : An.z; sa.w = m0 ? A0.w : An.w;
    sc.x = m0 ? C0.x : Cn.x; sc.y = m0 ? C0.y : Cn.y; sc.z = m0 ? C0.z : Cn.z; sc.w = m0 ? C0.w : Cn.w;
    if (si != 0 && si != nf){
      const float4* qs = AC + ((size_t)si*32 + lane)*2;
      sa = qs[0]; sc = qs[1];
    }
    float d = rA.x, d2 = d*d, ca = rA.z*d;
    float hx = fmaxf(fmaf(d, accx, fmaf(ca, sa.x, d2*sc.x)) + bb.x, 0.f);
    float hy = fmaxf(fmaf(d, accy, fmaf(ca, sa.y, d2*sc.y)) + bb.y, 0.f);
    float hz = fmaxf(fmaf(d, accz, fmaf(ca, sa.z, d2*sc.z)) + bb.z, 0.f);
    float hw = fmaxf(fmaf(d, accw, fmaf(ca, sa.w, d2*sc.w)) + bb.w, 0.f);
    float dsum = hx*owv.x + hy*owv.y + hz*owv.z + hw*owv.w;
    for (int o2 = 16; o2 > 0; o2 >>= 1) dsum += __shfl_down(dsum, o2, 32);
    if (lane == 0) recon[i] = tanhf(dsum + obv);
  }
}

// ---------------- launch ----------------
extern "C" void kernel_launch(void* const* d_in, const int* in_sizes, int n_in,
                              void* d_out, int out_size, void* d_ws, size_t ws_size,
                              hipStream_t stream){
  (void)in_sizes; (void)n_in; (void)out_size; (void)ws_size;
  const float* x      = (const float*)d_in[0];
  const float* eps    = (const float*)d_in[1];
  const float* enc_w1 = (const float*)d_in[2];
  const float* enc_b1 = (const float*)d_in[3];
  const float* enc_w2 = (const float*)d_in[4];
  const float* enc_b2 = (const float*)d_in[5];
  const float* mu_w   = (const float*)d_in[6];
  const float* mu_b   = (const float*)d_in[7];
  const float* lv_w   = (const float*)d_in[8];
  const float* lv_b   = (const float*)d_in[9];
  const float* zn_w   = (const float*)d_in[10];
  const float* zn_b   = (const float*)d_in[11];
  const float* dec_w1 = (const float*)d_in[12];
  const float* dec_b1 = (const float*)d_in[13];
  const float* dec_w2 = (const float*)d_in[14];
  const float* dec_b2 = (const float*)d_in[15];
  const float* out_w  = (const float*)d_in[16];
  const float* out_b  = (const float*)d_in[17];
  const int*   ei     = (const int*)d_in[18];

  float* out       = (float*)d_out;
  float* out_recon = out;
  float* out_mu    = out + NTOT;
  float* out_lv    = out_mu + BG*LD;
  float* out_z     = out_lv + BG*LD;

  char* w = (char*)d_ws;
  size_t off_b = 0;
  auto alloc = [&](size_t bytes)->void*{
    void* p = w + off_b;
    off_b += (bytes + 255) & ~(size_t)255;
    return p;
  };
  // region A (16MB): cntJ[0:4M) + accJ[4M:12M) early; sums4[0:16M) later
  char*   regA   = (char*) alloc((size_t)4*NTOT*16);
  int*    cntJ   = (int*)   regA;
  float2* accJ   = (float2*)(regA + (size_t)4*NTOT*4);
  float4* sums4  = (float4*)regA;
  float2* xd     = (float2*)alloc((size_t)NTOT*8);
  float4* rec    = (float4*)alloc((size_t)NTOT*16);
  float*  srowA  = (float*) alloc((size_t)NTOT*4);
  int2*   missL  = (int2*)  alloc((size_t)MCAP*8);
  float*  t1     = (float*) alloc(128*4);
  int*    nf1    = (int*)   alloc(256);
  int*    nf2    = (int*)   alloc(BG*4);
  int*    segU1  = (int*)   alloc(8*4);
  int*    segU   = (int*)   alloc(BG*8*4);
  float*  t2     = (float*) alloc((size_t)BG*HD*4);
  float*  ushG   = (float*) alloc((size_t)BG*HD*4);
  float*  AC1    = (float*) alloc((size_t)NSEG*256*4);
  float*  AC2    = (float*) alloc((size_t)BG*NSEG*256*4);
  float*  hgsum  = (float*) alloc((size_t)BG*HD*4);
  int*    mcnt   = (int*)   alloc(256);

  // 9 dispatches; zeroing + AC1 base rows folded into k_count's rider block

  k_count <<<257, 1024, 0, stream>>>(ei, enc_w1, enc_b1, enc_w2, cntJ, t1, nf1,
                                     AC1, hgsum, mcnt, segU1, segU);
  k_edge1 <<<256, 1024, 0, stream>>>(ei, cntJ, x, xd, accJ);
  k_pack  <<<NTOT/256, 256, 0, stream>>>(xd, accJ, t1, rec, srowA, segU1);

  k_edge2enc<<<257, 1024, 0, stream>>>(ei, rec, nf1, sums4, missL, mcnt,
                                       enc_w1, enc_b1, enc_w2, segU1, AC1);
  k_enc_fin <<<1024, 256, 0, stream>>>(rec, sums4, (const float4*)AC1, enc_b2,
                                       nf1, missL, mcnt, hgsum);

  k_small<<<BG, 1024, 0, stream>>>(hgsum, mu_w, mu_b, lv_w, lv_b, eps,
                                   zn_w, zn_b, dec_w1, dec_b1, dec_w2,
                                   out_mu, out_lv, out_z, t2, ushG, nf2, AC2);

  k_seg2<<<NTOT/256, 256, 0, stream>>>(t2, srowA, rec, segU);

  k_edge2dec<<<320, 1024, 0, stream>>>(ei, rec, nf2, sums4, missL, mcnt,
                                       ushG, dec_b1, dec_w2, segU, AC2);
  k_dec_fin <<<1024, 256, 0, stream>>>(rec, sums4, (const float4*)AC2, dec_b2,
                                       out_w, out_b, nf2, missL, mcnt, out_recon);
}